// Round 8
// baseline (671.349 us; speedup 1.0000x reference)
//
#include <hip/hip_runtime.h>
#include <hip/hip_bf16.h>
#include <math.h>

#define L_LAYERS 12
#define BATCH 8
#define SEQ 2048
#define HID 1024
#define DGATE 256
#define KTOT (L_LAYERS * HID)   // 12288
#define MTOT (BATCH * SEQ)      // 16384

typedef __attribute__((ext_vector_type(4))) float f32x4;
typedef __attribute__((ext_vector_type(8))) short bf16x8;
typedef unsigned short ushortT;

static __device__ __forceinline__ unsigned short f2bf(float x) {
    __hip_bfloat16 h = __float2bfloat16(x);
    return *reinterpret_cast<unsigned short*>(&h);
}

// ---------------- merged: pool(+bf16 convert of A) and transB ----------------
__global__ void streams_kernel(const float* __restrict__ lo, float* __restrict__ pooled,
                               ushortT* __restrict__ Abf, int doConv,
                               const float* __restrict__ W, ushortT* __restrict__ Bt) {
    __shared__ ushortT tile[64][72];
    int bid = blockIdx.x;
    int t = threadIdx.x;
    if (bid < 1536) {
        int lb = bid % 96;
        int sc = bid / 96;
        const float4* src = reinterpret_cast<const float4*>(lo + (size_t)lb * SEQ * HID);
        ushortT* dstb = Abf + (size_t)lb * SEQ * HID;
        float4 acc = {0.f, 0.f, 0.f, 0.f};
        int s0 = sc * 128;
        if (doConv) {
            #pragma unroll 4
            for (int s = s0; s < s0 + 128; ++s) {
                float4 v = src[(size_t)s * 256 + t];
                acc.x += v.x; acc.y += v.y; acc.z += v.z; acc.w += v.w;
                unsigned int u0 = (unsigned int)f2bf(v.x) | ((unsigned int)f2bf(v.y) << 16);
                unsigned int u1 = (unsigned int)f2bf(v.z) | ((unsigned int)f2bf(v.w) << 16);
                uint2 uu = {u0, u1};
                *reinterpret_cast<uint2*>(dstb + (size_t)s * HID + t * 4) = uu;
            }
        } else {
            #pragma unroll 4
            for (int s = s0; s < s0 + 128; ++s) {
                float4 v = src[(size_t)s * 256 + t];
                acc.x += v.x; acc.y += v.y; acc.z += v.z; acc.w += v.w;
            }
        }
        float* dst = pooled + (size_t)lb * HID + t * 4;
        atomicAdd(dst + 0, acc.x);
        atomicAdd(dst + 1, acc.y);
        atomicAdd(dst + 2, acc.z);
        atomicAdd(dst + 3, acc.w);
    } else {
        int idx = bid - 1536;
        int k0 = (idx % 192) * 64, n0 = (idx / 192) * 64;
        #pragma unroll
        for (int p = 0; p < 4; ++p) {
            int r = (t >> 4) + p * 16;
            int c = (t & 15) * 4;
            float4 v = *reinterpret_cast<const float4*>(W + (size_t)(k0 + r) * HID + n0 + c);
            tile[c + 0][r] = f2bf(v.x);
            tile[c + 1][r] = f2bf(v.y);
            tile[c + 2][r] = f2bf(v.z);
            tile[c + 3][r] = f2bf(v.w);
        }
        __syncthreads();
        #pragma unroll
        for (int p = 0; p < 2; ++p) {
            int idx2 = t + p * 256;
            int nl = idx2 >> 3;
            int kc = (idx2 & 7) * 8;
            uint4 v = *reinterpret_cast<const uint4*>(&tile[nl][kc]);
            *reinterpret_cast<uint4*>(Bt + (size_t)(n0 + nl) * KTOT + k0 + kc) = v;
        }
    }
}

// ---------------- gate MLP: one block per (l,b) ----------------
__global__ void gate_kernel(const float* __restrict__ pooled, const float* __restrict__ W1,
                            const float* __restrict__ b1, const float* __restrict__ lnw,
                            const float* __restrict__ lnb, const float* __restrict__ W2,
                            const float* __restrict__ b2, float* __restrict__ gate) {
    int lb = blockIdx.x;
    int l = lb >> 3;
    __shared__ float sp[HID];
    __shared__ float red[256];
    __shared__ float stat[2];
    int t = threadIdx.x;
    for (int i = t; i < HID; i += 256) sp[i] = pooled[(size_t)lb * HID + i] * (1.0f / 2048.0f);
    __syncthreads();
    const float* w1 = W1 + (size_t)l * HID * DGATE + t;
    float h = b1[l * DGATE + t];
    #pragma unroll 8
    for (int hh = 0; hh < HID; ++hh) h = fmaf(sp[hh], w1[(size_t)hh * DGATE], h);
    red[t] = h; __syncthreads();
    for (int o = 128; o > 0; o >>= 1) { if (t < o) red[t] += red[t + o]; __syncthreads(); }
    if (t == 0) stat[0] = red[0] * (1.0f / 256.0f);
    __syncthreads();
    float mu = stat[0];
    float c = h - mu;
    red[t] = c * c; __syncthreads();
    for (int o = 128; o > 0; o >>= 1) { if (t < o) red[t] += red[t + o]; __syncthreads(); }
    if (t == 0) stat[1] = red[0] * (1.0f / 256.0f);
    __syncthreads();
    float hn = c * rsqrtf(stat[1] + 1e-5f) * lnw[l * DGATE + t] + lnb[l * DGATE + t];
    float hg = hn * 0.5f * (1.0f + erff(hn * 0.70710678118654752f));
    red[t] = hg * W2[l * DGATE + t]; __syncthreads();
    for (int o = 128; o > 0; o >>= 1) { if (t < o) red[t] += red[t + o]; __syncthreads(); }
    if (t == 0) gate[lb] = 1.0f / (1.0f + expf(-(red[0] + b2[l])));
}

// ---------------- prep: m, w, ratios (Horner), bias ----------------
__global__ void prep_kernel(const float* __restrict__ cw, const float* __restrict__ U,
                            const float* __restrict__ V, const float* __restrict__ gate,
                            const float* __restrict__ projb, const int* __restrict__ cip,
                            float* __restrict__ wscale, float* __restrict__ ratio,
                            float* __restrict__ wfin, float* __restrict__ bias) {
    __shared__ float sm[L_LAYERS];
    __shared__ float sw[L_LAYERS * BATCH];
    int t = threadIdx.x;
    int ci = cip[0];
    if (t == 0) {
        float m[L_LAYERS];
        for (int i = 0; i < L_LAYERS; ++i) {
            float mm = cw[ci * L_LAYERS + i];
            float man = 0.f;
            for (int j = 0; j < 32; ++j) man = fmaf(U[ci * 32 + j], V[j * L_LAYERS + i], man);
            m[i] = 0.5f * mm + 0.5f * man;
        }
        for (int rep = 0; rep < 2; ++rep) {
            float mx = -1e30f;
            for (int i = 0; i < L_LAYERS; ++i) mx = fmaxf(mx, m[i]);
            float s = 0.f;
            for (int i = 0; i < L_LAYERS; ++i) { m[i] = expf(m[i] - mx); s += m[i]; }
            float inv = 1.0f / s;
            for (int i = 0; i < L_LAYERS; ++i) m[i] *= inv;
        }
        for (int i = 0; i < L_LAYERS; ++i) sm[i] = m[i];
    }
    __syncthreads();
    if (t < L_LAYERS * BATCH) {
        int l = t >> 3;
        float w = 0.9f * sm[l] * gate[t];
        sw[t] = w;
        wscale[t] = w;
    }
    __syncthreads();
    if (t < BATCH) {
        for (int l = 0; l < L_LAYERS; ++l) {
            float r = (l == 0) ? 1.0f : (sw[(l - 1) * BATCH + t] / sw[l * BATCH + t]);
            ratio[t * 16 + l] = r;
        }
        wfin[t] = sw[(L_LAYERS - 1) * BATCH + t];
    }
    for (int i = t; i < BATCH * HID; i += 256) {
        int b = i >> 10, k = i & 1023;
        float acc = 0.f;
        for (int l = 0; l < L_LAYERS; ++l) acc = fmaf(sw[l * BATCH + b], projb[l * HID + k], acc);
        bias[i] = acc;
    }
}

// ================= 256x256 8-phase GEMM, 16x16x32 MFMA, [256][64]+XOR(row&7), pipelined frags =================

#define MM(a, bb, c) __builtin_amdgcn_mfma_f32_16x16x32_bf16(a, bb, c, 0, 0, 0)

#define LDSA(d, off) (*(const bf16x8*)(ldsu + (d) * 16384 + (off)))
#define LDSB(d, off) (*(const bf16x8*)(ldsu + 32768 + (d) * 16384 + (off)))

// read A group g (rows 4g..4g+3 of wave's 8) k-half kk of buf d into dst[0..3]
#define RDA(dst, d, g, kk) { \
    dst[0] = LDSA(d, aK[kk] + ((g) * 4 + 0) * 1024); \
    dst[1] = LDSA(d, aK[kk] + ((g) * 4 + 1) * 1024); \
    dst[2] = LDSA(d, aK[kk] + ((g) * 4 + 2) * 1024); \
    dst[3] = LDSA(d, aK[kk] + ((g) * 4 + 3) * 1024); }

#define RDB(dst, d, kk) { \
    dst[0] = LDSB(d, bK[kk] + 0 * 1024); \
    dst[1] = LDSB(d, bK[kk] + 1 * 1024); \
    dst[2] = LDSB(d, bK[kk] + 2 * 1024); \
    dst[3] = LDSB(d, bK[kk] + 3 * 1024); }

#define MFMA16R(mb, A, B) { \
    acc[(mb)+0][0] = MM(A[0], B[0], acc[(mb)+0][0]); acc[(mb)+0][1] = MM(A[0], B[1], acc[(mb)+0][1]); \
    acc[(mb)+0][2] = MM(A[0], B[2], acc[(mb)+0][2]); acc[(mb)+0][3] = MM(A[0], B[3], acc[(mb)+0][3]); \
    acc[(mb)+1][0] = MM(A[1], B[0], acc[(mb)+1][0]); acc[(mb)+1][1] = MM(A[1], B[1], acc[(mb)+1][1]); \
    acc[(mb)+1][2] = MM(A[1], B[2], acc[(mb)+1][2]); acc[(mb)+1][3] = MM(A[1], B[3], acc[(mb)+1][3]); \
    acc[(mb)+2][0] = MM(A[2], B[0], acc[(mb)+2][0]); acc[(mb)+2][1] = MM(A[2], B[1], acc[(mb)+2][1]); \
    acc[(mb)+2][2] = MM(A[2], B[2], acc[(mb)+2][2]); acc[(mb)+2][3] = MM(A[2], B[3], acc[(mb)+2][3]); \
    acc[(mb)+3][0] = MM(A[3], B[0], acc[(mb)+3][0]); acc[(mb)+3][1] = MM(A[3], B[1], acc[(mb)+3][1]); \
    acc[(mb)+3][2] = MM(A[3], B[2], acc[(mb)+3][2]); acc[(mb)+3][3] = MM(A[3], B[3], acc[(mb)+3][3]); }

#define PH_BAR  __builtin_amdgcn_s_barrier(); __builtin_amdgcn_s_setprio(1);
#define PH_END  __builtin_amdgcn_s_setprio(0); __builtin_amdgcn_s_barrier(); __builtin_amdgcn_sched_barrier(0);
#define PH_ENDV(n) __builtin_amdgcn_s_setprio(0); \
    asm volatile("s_waitcnt vmcnt(" #n ")" ::: "memory"); \
    __builtin_amdgcn_s_barrier(); __builtin_amdgcn_sched_barrier(0);

__global__ __launch_bounds__(512, 2) void gemm8_kernel(
    const float* __restrict__ lo,
    const ushortT* __restrict__ Abf,          // bf16 A (L,B,S,H)
    const ushortT* __restrict__ Btp,          // bf16 Bt[n][k]
    const float* __restrict__ ratioP,         // [8][16]
    const float* __restrict__ wfinP,          // [8]
    const float* __restrict__ biasb,          // [8][1024]
    const int* __restrict__ cip,
    float* __restrict__ out)
{
    __shared__ ushortT ldsu[65536];           // 128 KiB

    const int tid = threadIdx.x;
    const int wid = tid >> 6, lane = tid & 63;
    const int wm = wid >> 2, wn = wid & 3;

    int bid = blockIdx.x;
    int xcd = bid & 7, local = bid >> 3;
    int mt = xcd * 8 + (local >> 2);          // 0..63
    int nt = local & 3;                       // 0..3
    int b = mt >> 3;
    int s0 = (mt & 7) << 8;
    int n0 = nt << 8;

    // ---- staging: thread covers physical chunk (row=tid>>3, c=tid&7) of a 64-row block;
    // global source chunk = c ^ (row&7).
    const int csrc = (tid & 7) ^ ((tid >> 3) & 7);
    const size_t aRow = (size_t)(tid >> 3) * HID + csrc * 8;
    const size_t bRow = (size_t)(n0 + (tid >> 3)) * KTOT + csrc * 8;
    const int ldst = tid * 8;
    const ushortT* aPlane0 = Abf + (size_t)b * (SEQ * HID) + (size_t)s0 * HID;

    auto stageA = [&](int d, int h, int kt) {
        int l = kt >> 4;
        const ushortT* plane = aPlane0 + (size_t)l * (BATCH * SEQ * HID) + ((kt & 15) << 6);
        #pragma unroll
        for (int j = 0; j < 2; ++j) {
            const ushortT* src = plane + (size_t)(h * 128 + j * 64) * HID + aRow;
            ushortT* dst = ldsu + d * 16384 + (h * 128 + j * 64) * 64 + ldst;
            __builtin_amdgcn_global_load_lds(
                (const __attribute__((address_space(1))) void*)src,
                (__attribute__((address_space(3))) void*)dst, 16, 0, 0);
        }
    };
    auto stageB = [&](int d, int h, int kt) {
        const ushortT* baseB = Btp + ((size_t)kt << 6);
        #pragma unroll
        for (int j = 0; j < 2; ++j) {
            const ushortT* src = baseB + (size_t)(h * 128 + j * 64) * KTOT + bRow;
            ushortT* dst = ldsu + 32768 + d * 16384 + (h * 128 + j * 64) * 64 + ldst;
            __builtin_amdgcn_global_load_lds(
                (const __attribute__((address_space(1))) void*)src,
                (__attribute__((address_space(3))) void*)dst, 16, 0, 0);
        }
    };

    // ---- fragment base offsets (ushorts). row = base + frag*16 + (lane&15); frag spacing = 1024.
    // logical chunk = kk*4 + (lane>>4); physical = logical ^ (row&7); row&7 == lane&7.
    int aK[2], bK[2];
    {
        int kb = lane >> 4;
        int c0 = ((kb + 0) ^ (lane & 7)) * 8;
        int c1 = ((kb + 4) ^ (lane & 7)) * 8;
        int ar = (wm * 128 + (lane & 15)) * 64;
        int br = (wn * 64 + (lane & 15)) * 64;
        aK[0] = ar + c0; aK[1] = ar + c1;
        bK[0] = br + c0; bK[1] = br + c1;
    }

    f32x4 acc[8][4];
    #pragma unroll
    for (int m = 0; m < 8; ++m)
        #pragma unroll
        for (int n = 0; n < 4; ++n)
            acc[m][n] = (f32x4){0.f, 0.f, 0.f, 0.f};

    // ---- prologue: A0<-t0 (4), B0<-t0 (4), B1<-t1 (4); first 8 must land.
    stageA(0, 0, 0); stageA(0, 1, 0);
    stageB(0, 0, 0); stageB(0, 1, 0);
    stageB(1, 0, 1); stageB(1, 1, 1);
    asm volatile("s_waitcnt vmcnt(4)" ::: "memory");
    __builtin_amdgcn_s_barrier();
    __builtin_amdgcn_sched_barrier(0);

    bf16x8 avX[4], avY[4], bvX[4], bvY[4];

    #pragma unroll 1
    for (int i = 0; i < 95; ++i) {
        int t1 = 2 * i + 1;
        if (i && !(i & 7)) {                  // entering a new layer: Horner rescale
            float rr = ratioP[b * 16 + (i >> 3)];
            #pragma unroll
            for (int m = 0; m < 8; ++m)
                #pragma unroll
                for (int n = 0; n < 4; ++n)
                    acc[m][n] *= rr;
        }
        // P1: own frags + pre-issue P2's A
        RDA(avX, 0, 0, 0); RDB(bvX, 0, 0); RDA(avY, 0, 1, 0);
        stageA(1, 0, t1);
        PH_BAR; MFMA16R(0, avX, bvX); PH_END;
        // P2: pre-issue P3 (A kk1 rows0-3 + B kk1)
        RDA(avX, 0, 0, 1); RDB(bvY, 0, 1);
        stageA(1, 1, t1);
        PH_BAR; MFMA16R(4, avY, bvX); PH_END;
        // P3: pre-issue P4 (A kk1 rows4-7)
        RDA(avY, 0, 1, 1);
        PH_BAR; MFMA16R(0, avX, bvY); PH_END;
        // P4: stage B0<-t0+2; vmcnt(4) drains prev-B1 + A1 (leaves own B0)
        stageB(0, 0, t1 + 1); stageB(0, 1, t1 + 1);
        PH_BAR; MFMA16R(4, avY, bvY); PH_ENDV(4);
        // P5: buf1 now guaranteed; own frags + pre-issue P6's A
        RDA(avX, 1, 0, 0); RDB(bvX, 1, 0); RDA(avY, 1, 1, 0);
        stageA(0, 0, t1 + 1);
        PH_BAR; MFMA16R(0, avX, bvX); PH_END;
        // P6: pre-issue P7
        RDA(avX, 1, 0, 1); RDB(bvY, 1, 1);
        stageA(0, 1, t1 + 1);
        PH_BAR; MFMA16R(4, avY, bvX); PH_END;
        // P7: pre-issue P8
        RDA(avY, 1, 1, 1);
        PH_BAR; MFMA16R(0, avX, bvY); PH_END;
        // P8: stage B1<-t1+2; vmcnt(4) drains B0 + A0 (leaves own B1)
        stageB(1, 0, t1 + 2); stageB(1, 1, t1 + 2);
        PH_BAR; MFMA16R(4, avY, bvY); PH_ENDV(4);
    }

    // final iteration (t0=190 buf0, t1=191 buf1); A1<-191 staged here
    {
        RDA(avX, 0, 0, 0); RDB(bvX, 0, 0); RDA(avY, 0, 1, 0);
        stageA(1, 0, 191);
        PH_BAR; MFMA16R(0, avX, bvX); PH_END;
        RDA(avX, 0, 0, 1); RDB(bvY, 0, 1);
        stageA(1, 1, 191);
        PH_BAR; MFMA16R(4, avY, bvX); PH_END;
        RDA(avY, 0, 1, 1);
        PH_BAR; MFMA16R(0, avX, bvY); PH_END;
        PH_BAR; MFMA16R(4, avY, bvY); PH_ENDV(0);
        RDA(avX, 1, 0, 0); RDB(bvX, 1, 0); RDA(avY, 1, 1, 0);
        PH_BAR; MFMA16R(0, avX, bvX); PH_END;
        RDA(avX, 1, 0, 1); RDB(bvY, 1, 1);
        PH_BAR; MFMA16R(4, avY, bvX); PH_END;
        RDA(avY, 1, 1, 1);
        PH_BAR; MFMA16R(0, avX, bvY); PH_END;
        PH_BAR; MFMA16R(4, avY, bvY);
        __builtin_amdgcn_s_setprio(0);
    }
    __syncthreads();

    // ---------- LDS-staged vectorized epilogue ----------
    // C/D 16x16 layout: col = lane&15, row = (lane>>4)*4 + r.
    // Stagger: column 16-block XOR'd by ((rl>>2)&1)*16 to keep the scatter 2-way.
    int ci = cip[0];
    float wf = wfinP[b];
    const float* resid = lo + (((size_t)ci * BATCH + b) * SEQ + s0) * HID;
    float* op = out + ((size_t)b * SEQ + s0) * HID;
    float* ldsf = reinterpret_cast<float*>(ldsu);

    int rl16 = tid >> 4;          // 0..31
    int c16 = tid & 15;

    #pragma unroll 1
    for (int chunk = 0; chunk < 2; ++chunk) {
        if (wm == chunk) {
            #pragma unroll
            for (int m = 0; m < 8; ++m) {
                int rbase = m * 16 + (lane >> 4) * 4;
                #pragma unroll
                for (int n = 0; n < 4; ++n) {
                    int col64 = n * 16 + (lane & 15);
                    #pragma unroll
                    for (int r = 0; r < 4; ++r) {
                        int rl = rbase + r;
                        int colw = wn * 64 + (col64 ^ (((rl >> 2) & 1) << 4));
                        ldsf[rl * 256 + colw] = acc[m][n][r];
                    }
                }
            }
        }
        __syncthreads();
        #pragma unroll
        for (int p = 0; p < 4; ++p) {
            int rloc = p * 32 + rl16;
            int stag = ((rloc >> 2) & 1) << 4;
            int grow = chunk * 128 + rloc;
            const float* rrow = resid + (size_t)grow * HID + n0;
            float* orow = op + (size_t)grow * HID + n0;
            const float* brow = biasb + b * HID + n0;
            const float* lrow = ldsf + rloc * 256;
            #pragma unroll
            for (int seg = 0; seg < 4; ++seg) {
                int cl = seg * 64 + c16 * 4;
                float4 v = *reinterpret_cast<const float4*>(lrow + (cl ^ stag));
                float4 bs = *reinterpret_cast<const float4*>(brow + cl);
                float4 rs = *reinterpret_cast<const float4*>(rrow + cl);
                float4 o;
                o.x = v.x * wf + bs.x + rs.x;
                o.y = v.y * wf + bs.y + rs.y;
                o.z = v.z * wf + bs.z + rs.z;
                o.w = v.w * wf + bs.w + rs.w;
                *reinterpret_cast<float4*>(orow + cl) = o;
            }
        }
        __syncthreads();
    }
}

// ---------------- fallback: round-2 128^2 gload_lds GEMM (proven) ----------------
#define BM 128
#define BN 128
#define BK 64
#define NT (KTOT / BK)    // 192

__global__ __launch_bounds__(256, 2) void gemm128_kernel(
    const float* __restrict__ lo, const ushortT* __restrict__ Abf,
    const ushortT* __restrict__ Btp, const float* __restrict__ ratioP,
    const float* __restrict__ wfinP, const float* __restrict__ biasb,
    const int* __restrict__ cip, float* __restrict__ out)
{
    __shared__ ushortT lA[2][BM * BK];
    __shared__ ushortT lB[2][BN * BK];
    int t = threadIdx.x;
    int bid = blockIdx.x;
    int xcd = bid & 7, local = bid >> 3;
    int by = xcd * 16 + (local >> 3);
    int bx = local & 7;
    int b = by >> 4;
    int s0 = (by & 15) << 7;
    int n0 = bx << 7;
    int wid = t >> 6, lane = t & 63;
    int wr = wid >> 1, wc = wid & 1;
    int m16 = lane & 15, kb = lane >> 4;
    int aBase[4], bBase[4], ldsBase[4];
    #pragma unroll
    for (int i = 0; i < 4; ++i) {
        int ci2 = i * 256 + t;
        int row = ci2 >> 3, c = ci2 & 7;
        int sw = c ^ (row & 7);
        aBase[i] = (s0 + row) * HID + sw * 8;
        bBase[i] = (n0 + row) * KTOT + sw * 8;
        ldsBase[i] = i * 2048 + wid * 512;
    }
    int aoff[4][2], boff[4][2];
    #pragma unroll
    for (int i = 0; i < 4; ++i) {
        int ra = wr * 64 + i * 16 + m16;
        int rb = wc * 64 + i * 16 + m16;
        #pragma unroll
        for (int kk = 0; kk < 2; ++kk) {
            aoff[i][kk] = ra * 64 + (((kb + 4 * kk) ^ (ra & 7)) * 8);
            boff[i][kk] = rb * 64 + (((kb + 4 * kk) ^ (rb & 7)) * 8);
        }
    }
    f32x4 acc[4][4];
    #pragma unroll
    for (int i = 0; i < 4; ++i)
        #pragma unroll
        for (int j = 0; j < 4; ++j)
            acc[i][j] = (f32x4){0.f, 0.f, 0.f, 0.f};
    auto stage = [&](int buf, int tk2) {
        int l = tk2 >> 4;
        const ushortT* aT = Abf + (size_t)(l * BATCH + b) * (SEQ * HID) + ((tk2 & 15) << 6);
        const ushortT* bT = Btp + ((size_t)tk2 << 6);
        ushortT* la = &lA[buf][0];
        ushortT* lb = &lB[buf][0];
        #pragma unroll
        for (int i = 0; i < 4; ++i)
            __builtin_amdgcn_global_load_lds(
                (const __attribute__((address_space(1))) void*)(aT + aBase[i]),
                (__attribute__((address_space(3))) void*)(la + ldsBase[i]), 16, 0, 0);
        #pragma unroll
        for (int i = 0; i < 4; ++i)
            __builtin_amdgcn_global_load_lds(
                (const __attribute__((address_space(1))) void*)(bT + bBase[i]),
                (__attribute__((address_space(3))) void*)(lb + ldsBase[i]), 16, 0, 0);
    };
    stage(0, 0);
    __syncthreads();
    for (int tk = 0; tk < NT; ++tk) {
        int cur = tk & 1;
        if (tk + 1 < NT) stage(cur ^ 1, tk + 1);
        bf16x8 av[4][2], bv[4][2];
        #pragma unroll
        for (int i = 0; i < 4; ++i) {
            av[i][0] = *reinterpret_cast<const bf16x8*>(&lA[cur][aoff[i][0]]);
            av[i][1] = *reinterpret_cast<const bf16x8*>(&lA[cur][aoff[i][1]]);
            bv[i][0] = *reinterpret_cast<const bf16x8*>(&lB[cur][boff[i][0]]);
            bv[i][1] = *reinterpret_cast<const bf16x8*>(&lB[cur][boff[i][1]]);
        }
        if ((tk & 15) == 0 && tk) {
            float rr = ratioP[b * 16 + (tk >> 4)];
            #pragma unroll
            for (int i = 0; i < 4; ++i)
                #pragma unroll
                for (int j = 0; j < 4; ++j)
                    acc[i][j] = acc[i][j] * rr;
        }
        #pragma unroll
        for (int kk = 0; kk < 2; ++kk)
            #pragma unroll
            for (int fm = 0; fm < 4; ++fm)
                #pragma unroll
                for (int fn = 0; fn < 4; ++fn)
                    acc[fm][fn] = MM(av[fm][kk], bv[fn][kk], acc[fm][fn]);
        __syncthreads();
    }
    int ci = cip[0];
    float wf = wfinP[b];
    const float* resid = lo + (((size_t)ci * BATCH + b) * SEQ + s0) * HID;
    float* op = out + ((size_t)b * SEQ + s0) * HID;
    #pragma unroll
    for (int fn = 0; fn < 4; ++fn) {
        int col = n0 + wc * 64 + fn * 16 + m16;
        float bs = biasb[b * HID + col];
        #pragma unroll
        for (int fm = 0; fm < 4; ++fm) {
            int rbase = wr * 64 + fm * 16 + kb * 4;
            #pragma unroll
            for (int r = 0; r < 4; ++r) {
                float v = acc[fm][fn][r] * wf + bs + resid[(size_t)(rbase + r) * HID + col];
                op[(size_t)(rbase + r) * HID + col] = v;
            }
        }
    }
}

extern "C" void kernel_launch(void* const* d_in, const int* in_sizes, int n_in,
                              void* d_out, int out_size, void* d_ws, size_t ws_size,
                              hipStream_t stream) {
    const float* lo  = (const float*)d_in[0];
    const float* cw  = (const float*)d_in[1];
    const float* mU  = (const float*)d_in[2];
    const float* mV  = (const float*)d_in[3];
    const float* W1  = (const float*)d_in[4];
    const float* b1  = (const float*)d_in[5];
    const float* lnw = (const float*)d_in[6];
    const float* lnb = (const float*)d_in[7];
    const float* W2  = (const float*)d_in[8];
    const float* b2  = (const float*)d_in[9];
    const float* pW  = (const float*)d_in[10];
    const float* pb  = (const float*)d_in[11];
    const int*   ci  = (const int*)d_in[12];
    float* out = (float*)d_out;

    float* pooled = (float*)d_ws;                          // 98304 f
    float* gateb  = pooled + 98304;
    float* wsc    = gateb + 96;
    float* ratio  = wsc + 96;
    float* wfin   = ratio + 128;
    float* biasb  = wfin + 8;
    ushortT* Btp  = (ushortT*)((char*)d_ws + 458752);      // 25165824 B
    ushortT* Abf  = (ushortT*)((char*)d_ws + 25624576);    // 402653184 B
    const size_t need = 25624576ULL + 402653184ULL;

    int fast = (ws_size >= need) ? 1 : 0;

    hipMemsetAsync(pooled, 0, 98304 * sizeof(float), stream);
    streams_kernel<<<dim3(1536 + 3072), 256, 0, stream>>>(lo, pooled, Abf, fast, pW, Btp);
    gate_kernel<<<96, 256, 0, stream>>>(pooled, W1, b1, lnw, lnb, W2, b2, gateb);
    prep_kernel<<<1, 256, 0, stream>>>(cw, mU, mV, gateb, pb, ci, wsc, ratio, wfin, biasb);
    if (fast) {
        gemm8_kernel<<<dim3(256), 512, 0, stream>>>(lo, Abf, Btp, ratio, wfin, biasb, ci, out);
    } else {
        gemm128_kernel<<<dim3(1024), 256, 0, stream>>>(lo, Abf, Btp, ratio, wfin, biasb, ci, out);
    }
}

// Round 9
// 658.030 us; speedup vs baseline: 1.0202x; 1.0202x over previous
//
#include <hip/hip_runtime.h>
#include <hip/hip_bf16.h>
#include <math.h>

#define L_LAYERS 12
#define BATCH 8
#define SEQ 2048
#define HID 1024
#define DGATE 256
#define KTOT (L_LAYERS * HID)   // 12288
#define MTOT (BATCH * SEQ)      // 16384

typedef __attribute__((ext_vector_type(4))) float f32x4;
typedef __attribute__((ext_vector_type(8))) short bf16x8;
typedef unsigned short ushortT;

static __device__ __forceinline__ unsigned short f2bf(float x) {
    __hip_bfloat16 h = __float2bfloat16(x);
    return *reinterpret_cast<unsigned short*>(&h);
}

// ---------------- merged: pool(+bf16 convert of A) and transB ----------------
__global__ void streams_kernel(const float* __restrict__ lo, float* __restrict__ pooled,
                               ushortT* __restrict__ Abf, int doConv,
                               const float* __restrict__ W, ushortT* __restrict__ Bt) {
    __shared__ ushortT tile[64][72];
    int bid = blockIdx.x;
    int t = threadIdx.x;
    if (bid < 1536) {
        int lb = bid % 96;
        int sc = bid / 96;
        const float4* src = reinterpret_cast<const float4*>(lo + (size_t)lb * SEQ * HID);
        ushortT* dstb = Abf + (size_t)lb * SEQ * HID;
        float4 acc = {0.f, 0.f, 0.f, 0.f};
        int s0 = sc * 128;
        if (doConv) {
            #pragma unroll 4
            for (int s = s0; s < s0 + 128; ++s) {
                float4 v = src[(size_t)s * 256 + t];
                acc.x += v.x; acc.y += v.y; acc.z += v.z; acc.w += v.w;
                unsigned int u0 = (unsigned int)f2bf(v.x) | ((unsigned int)f2bf(v.y) << 16);
                unsigned int u1 = (unsigned int)f2bf(v.z) | ((unsigned int)f2bf(v.w) << 16);
                uint2 uu = {u0, u1};
                *reinterpret_cast<uint2*>(dstb + (size_t)s * HID + t * 4) = uu;
            }
        } else {
            #pragma unroll 4
            for (int s = s0; s < s0 + 128; ++s) {
                float4 v = src[(size_t)s * 256 + t];
                acc.x += v.x; acc.y += v.y; acc.z += v.z; acc.w += v.w;
            }
        }
        float* dst = pooled + (size_t)lb * HID + t * 4;
        atomicAdd(dst + 0, acc.x);
        atomicAdd(dst + 1, acc.y);
        atomicAdd(dst + 2, acc.z);
        atomicAdd(dst + 3, acc.w);
    } else {
        int idx = bid - 1536;
        int k0 = (idx % 192) * 64, n0 = (idx / 192) * 64;
        #pragma unroll
        for (int p = 0; p < 4; ++p) {
            int r = (t >> 4) + p * 16;
            int c = (t & 15) * 4;
            float4 v = *reinterpret_cast<const float4*>(W + (size_t)(k0 + r) * HID + n0 + c);
            tile[c + 0][r] = f2bf(v.x);
            tile[c + 1][r] = f2bf(v.y);
            tile[c + 2][r] = f2bf(v.z);
            tile[c + 3][r] = f2bf(v.w);
        }
        __syncthreads();
        #pragma unroll
        for (int p = 0; p < 2; ++p) {
            int idx2 = t + p * 256;
            int nl = idx2 >> 3;
            int kc = (idx2 & 7) * 8;
            uint4 v = *reinterpret_cast<const uint4*>(&tile[nl][kc]);
            *reinterpret_cast<uint4*>(Bt + (size_t)(n0 + nl) * KTOT + k0 + kc) = v;
        }
    }
}

// ---------------- gate MLP: one block per (l,b) ----------------
__global__ void gate_kernel(const float* __restrict__ pooled, const float* __restrict__ W1,
                            const float* __restrict__ b1, const float* __restrict__ lnw,
                            const float* __restrict__ lnb, const float* __restrict__ W2,
                            const float* __restrict__ b2, float* __restrict__ gate) {
    int lb = blockIdx.x;
    int l = lb >> 3;
    __shared__ float sp[HID];
    __shared__ float red[256];
    __shared__ float stat[2];
    int t = threadIdx.x;
    for (int i = t; i < HID; i += 256) sp[i] = pooled[(size_t)lb * HID + i] * (1.0f / 2048.0f);
    __syncthreads();
    const float* w1 = W1 + (size_t)l * HID * DGATE + t;
    float h = b1[l * DGATE + t];
    #pragma unroll 8
    for (int hh = 0; hh < HID; ++hh) h = fmaf(sp[hh], w1[(size_t)hh * DGATE], h);
    red[t] = h; __syncthreads();
    for (int o = 128; o > 0; o >>= 1) { if (t < o) red[t] += red[t + o]; __syncthreads(); }
    if (t == 0) stat[0] = red[0] * (1.0f / 256.0f);
    __syncthreads();
    float mu = stat[0];
    float c = h - mu;
    red[t] = c * c; __syncthreads();
    for (int o = 128; o > 0; o >>= 1) { if (t < o) red[t] += red[t + o]; __syncthreads(); }
    if (t == 0) stat[1] = red[0] * (1.0f / 256.0f);
    __syncthreads();
    float hn = c * rsqrtf(stat[1] + 1e-5f) * lnw[l * DGATE + t] + lnb[l * DGATE + t];
    float hg = hn * 0.5f * (1.0f + erff(hn * 0.70710678118654752f));
    red[t] = hg * W2[l * DGATE + t]; __syncthreads();
    for (int o = 128; o > 0; o >>= 1) { if (t < o) red[t] += red[t + o]; __syncthreads(); }
    if (t == 0) gate[lb] = 1.0f / (1.0f + expf(-(red[0] + b2[l])));
}

// ---------------- prep: m, w, ratios (Horner), bias ----------------
__global__ void prep_kernel(const float* __restrict__ cw, const float* __restrict__ U,
                            const float* __restrict__ V, const float* __restrict__ gate,
                            const float* __restrict__ projb, const int* __restrict__ cip,
                            float* __restrict__ wscale, float* __restrict__ ratio,
                            float* __restrict__ wfin, float* __restrict__ bias) {
    __shared__ float sm[L_LAYERS];
    __shared__ float sw[L_LAYERS * BATCH];
    int t = threadIdx.x;
    int ci = cip[0];
    if (t == 0) {
        float m[L_LAYERS];
        for (int i = 0; i < L_LAYERS; ++i) {
            float mm = cw[ci * L_LAYERS + i];
            float man = 0.f;
            for (int j = 0; j < 32; ++j) man = fmaf(U[ci * 32 + j], V[j * L_LAYERS + i], man);
            m[i] = 0.5f * mm + 0.5f * man;
        }
        for (int rep = 0; rep < 2; ++rep) {
            float mx = -1e30f;
            for (int i = 0; i < L_LAYERS; ++i) mx = fmaxf(mx, m[i]);
            float s = 0.f;
            for (int i = 0; i < L_LAYERS; ++i) { m[i] = expf(m[i] - mx); s += m[i]; }
            float inv = 1.0f / s;
            for (int i = 0; i < L_LAYERS; ++i) m[i] *= inv;
        }
        for (int i = 0; i < L_LAYERS; ++i) sm[i] = m[i];
    }
    __syncthreads();
    if (t < L_LAYERS * BATCH) {
        int l = t >> 3;
        float w = 0.9f * sm[l] * gate[t];
        sw[t] = w;
        wscale[t] = w;
    }
    __syncthreads();
    if (t < BATCH) {
        for (int l = 0; l < L_LAYERS; ++l) {
            float r = (l == 0) ? 1.0f : (sw[(l - 1) * BATCH + t] / sw[l * BATCH + t]);
            ratio[t * 16 + l] = r;
        }
        wfin[t] = sw[(L_LAYERS - 1) * BATCH + t];
    }
    for (int i = t; i < BATCH * HID; i += 256) {
        int b = i >> 10, k = i & 1023;
        float acc = 0.f;
        for (int l = 0; l < L_LAYERS; ++l) acc = fmaf(sw[l * BATCH + b], projb[l * HID + k], acc);
        bias[i] = acc;
    }
}

// ============ 256x256 8-phase GEMM, 16x16x32 MFMA, [256][64]+XOR(row&7), 1 barrier/phase ============

#define MM(a, bb, c) __builtin_amdgcn_mfma_f32_16x16x32_bf16(a, bb, c, 0, 0, 0)

#define LDSA(d, off) (*(const bf16x8*)(ldsu + (d) * 16384 + (off)))
#define LDSB(d, off) (*(const bf16x8*)(ldsu + 32768 + (d) * 16384 + (off)))

// kk in {0,1}: 32-k half of the K=64 tile
#define READ_AB(d, kk) { \
    av[0] = LDSA(d, aoff[0][kk]); av[1] = LDSA(d, aoff[1][kk]); \
    av[2] = LDSA(d, aoff[2][kk]); av[3] = LDSA(d, aoff[3][kk]); \
    bv[0] = LDSB(d, boff[0][kk]); bv[1] = LDSB(d, boff[1][kk]); \
    bv[2] = LDSB(d, boff[2][kk]); bv[3] = LDSB(d, boff[3][kk]); }

#define READ_A2(d, kk) { \
    av[0] = LDSA(d, aoff[4][kk]); av[1] = LDSA(d, aoff[5][kk]); \
    av[2] = LDSA(d, aoff[6][kk]); av[3] = LDSA(d, aoff[7][kk]); }

#define MFMA16(mb) { \
    acc[(mb)+0][0] = MM(av[0], bv[0], acc[(mb)+0][0]); acc[(mb)+0][1] = MM(av[0], bv[1], acc[(mb)+0][1]); \
    acc[(mb)+0][2] = MM(av[0], bv[2], acc[(mb)+0][2]); acc[(mb)+0][3] = MM(av[0], bv[3], acc[(mb)+0][3]); \
    acc[(mb)+1][0] = MM(av[1], bv[0], acc[(mb)+1][0]); acc[(mb)+1][1] = MM(av[1], bv[1], acc[(mb)+1][1]); \
    acc[(mb)+1][2] = MM(av[1], bv[2], acc[(mb)+1][2]); acc[(mb)+1][3] = MM(av[1], bv[3], acc[(mb)+1][3]); \
    acc[(mb)+2][0] = MM(av[2], bv[0], acc[(mb)+2][0]); acc[(mb)+2][1] = MM(av[2], bv[1], acc[(mb)+2][1]); \
    acc[(mb)+2][2] = MM(av[2], bv[2], acc[(mb)+2][2]); acc[(mb)+2][3] = MM(av[2], bv[3], acc[(mb)+2][3]); \
    acc[(mb)+3][0] = MM(av[3], bv[0], acc[(mb)+3][0]); acc[(mb)+3][1] = MM(av[3], bv[1], acc[(mb)+3][1]); \
    acc[(mb)+3][2] = MM(av[3], bv[2], acc[(mb)+3][2]); acc[(mb)+3][3] = MM(av[3], bv[3], acc[(mb)+3][3]); }

#define PH_GO   __builtin_amdgcn_s_setprio(1);
#define PH_END  __builtin_amdgcn_s_setprio(0); __builtin_amdgcn_s_barrier(); __builtin_amdgcn_sched_barrier(0);
#define PH_ENDV(n) __builtin_amdgcn_s_setprio(0); \
    asm volatile("s_waitcnt vmcnt(" #n ")" ::: "memory"); \
    __builtin_amdgcn_s_barrier(); __builtin_amdgcn_sched_barrier(0);

__global__ __launch_bounds__(512, 2) void gemm8_kernel(
    const float* __restrict__ lo,
    const ushortT* __restrict__ Abf,          // bf16 A (L,B,S,H)
    const ushortT* __restrict__ Btp,          // bf16 Bt[n][k]
    const float* __restrict__ ratioP,         // [8][16]
    const float* __restrict__ wfinP,          // [8]
    const float* __restrict__ biasb,          // [8][1024]
    const int* __restrict__ cip,
    float* __restrict__ out)
{
    __shared__ ushortT ldsu[65536];           // 128 KiB

    const int tid = threadIdx.x;
    const int wid = tid >> 6, lane = tid & 63;
    const int wm = wid >> 2, wn = wid & 3;

    int bid = blockIdx.x;
    int xcd = bid & 7, local = bid >> 3;
    int mt = xcd * 8 + (local >> 2);          // 0..63
    int nt = local & 3;                       // 0..3
    int b = mt >> 3;
    int s0 = (mt & 7) << 8;
    int n0 = nt << 8;

    // ---- staging: thread covers physical chunk (row=tid>>3, c=tid&7) of a 64-row block;
    // global source chunk = c ^ (row&7).
    const int csrc = (tid & 7) ^ ((tid >> 3) & 7);
    const size_t aRow = (size_t)(tid >> 3) * HID + csrc * 8;
    const size_t bRow = (size_t)(n0 + (tid >> 3)) * KTOT + csrc * 8;
    const int ldst = tid * 8;
    const ushortT* aPlane0 = Abf + (size_t)b * (SEQ * HID) + (size_t)s0 * HID;

    auto stageA = [&](int d, int h, int kt) {
        int l = kt >> 4;
        const ushortT* plane = aPlane0 + (size_t)l * (BATCH * SEQ * HID) + ((kt & 15) << 6);
        #pragma unroll
        for (int j = 0; j < 2; ++j) {
            const ushortT* src = plane + (size_t)(h * 128 + j * 64) * HID + aRow;
            ushortT* dst = ldsu + d * 16384 + (h * 128 + j * 64) * 64 + ldst;
            __builtin_amdgcn_global_load_lds(
                (const __attribute__((address_space(1))) void*)src,
                (__attribute__((address_space(3))) void*)dst, 16, 0, 0);
        }
    };
    auto stageB = [&](int d, int h, int kt) {
        const ushortT* baseB = Btp + ((size_t)kt << 6);
        #pragma unroll
        for (int j = 0; j < 2; ++j) {
            const ushortT* src = baseB + (size_t)(h * 128 + j * 64) * KTOT + bRow;
            ushortT* dst = ldsu + 32768 + d * 16384 + (h * 128 + j * 64) * 64 + ldst;
            __builtin_amdgcn_global_load_lds(
                (const __attribute__((address_space(1))) void*)src,
                (__attribute__((address_space(3))) void*)dst, 16, 0, 0);
        }
    };

    // ---- ds_read fragment offsets (ushorts within a [256][64] tile)
    // 16x16x32 A/B frag: row = base + f*16 + (lane&15); logical chunk = kk*4 + (lane>>4);
    // physical chunk = logical ^ (row&7); row&7 == (lane&7).
    int csw[2];
    {
        int kb = lane >> 4;
        csw[0] = ((kb + 0) ^ (lane & 7)) * 8;
        csw[1] = ((kb + 4) ^ (lane & 7)) * 8;
    }
    int aoff[8][2], boff[4][2];
    #pragma unroll
    for (int m = 0; m < 8; ++m) {
        int row = wm * 128 + m * 16 + (lane & 15);
        aoff[m][0] = row * 64 + csw[0];
        aoff[m][1] = row * 64 + csw[1];
    }
    #pragma unroll
    for (int n = 0; n < 4; ++n) {
        int row = wn * 64 + n * 16 + (lane & 15);
        boff[n][0] = row * 64 + csw[0];
        boff[n][1] = row * 64 + csw[1];
    }

    f32x4 acc[8][4];
    #pragma unroll
    for (int m = 0; m < 8; ++m)
        #pragma unroll
        for (int n = 0; n < 4; ++n)
            acc[m][n] = (f32x4){0.f, 0.f, 0.f, 0.f};

    // ---- prologue: A0<-t0 (4), B0<-t0 (4), B1<-t1 (4); first 8 must land.
    stageA(0, 0, 0); stageA(0, 1, 0);
    stageB(0, 0, 0); stageB(0, 1, 0);
    stageB(1, 0, 1); stageB(1, 1, 1);
    asm volatile("s_waitcnt vmcnt(4)" ::: "memory");
    __builtin_amdgcn_s_barrier();
    __builtin_amdgcn_sched_barrier(0);

    bf16x8 av[4], bv[4];

    #pragma unroll 1
    for (int i = 0; i < 95; ++i) {
        int t1 = 2 * i + 1;
        if (i && !(i & 7)) {                  // entering a new layer: Horner rescale
            float rr = ratioP[b * 16 + (i >> 3)];
            #pragma unroll
            for (int m = 0; m < 8; ++m)
                #pragma unroll
                for (int n = 0; n < 4; ++n)
                    acc[m][n] *= rr;
        }
        // P1
        READ_AB(0, 0); stageA(1, 0, t1);                           PH_GO; MFMA16(0); PH_END;
        // P2
        READ_A2(0, 0); stageA(1, 1, t1);                           PH_GO; MFMA16(4); PH_END;
        // P3
        READ_AB(0, 1);                                             PH_GO; MFMA16(0); PH_END;
        // P4  (stage B0 <- t0+2; drain prev-B1 + A1, leave own 4)
        READ_A2(0, 1); stageB(0, 0, t1 + 1); stageB(0, 1, t1 + 1); PH_GO; MFMA16(4); PH_ENDV(4);
        // P5
        READ_AB(1, 0); stageA(0, 0, t1 + 1);                       PH_GO; MFMA16(0); PH_END;
        // P6
        READ_A2(1, 0); stageA(0, 1, t1 + 1);                       PH_GO; MFMA16(4); PH_END;
        // P7
        READ_AB(1, 1);                                             PH_GO; MFMA16(0); PH_END;
        // P8  (stage B1 <- t1+2; drain B0 + A0, leave own 4)
        READ_A2(1, 1); stageB(1, 0, t1 + 2); stageB(1, 1, t1 + 2); PH_GO; MFMA16(4); PH_ENDV(4);
    }

    // final iteration (t0=190 in buf0, t1=191 in buf1)
    {
        READ_AB(0, 0); stageA(1, 0, 191);  PH_GO; MFMA16(0); PH_END;
        READ_A2(0, 0); stageA(1, 1, 191);  PH_GO; MFMA16(4); PH_END;
        READ_AB(0, 1);                     PH_GO; MFMA16(0); PH_END;
        READ_A2(0, 1);                     PH_GO; MFMA16(4); PH_ENDV(0);
        READ_AB(1, 0);                     PH_GO; MFMA16(0); PH_END;
        READ_A2(1, 0);                     PH_GO; MFMA16(4); PH_END;
        READ_AB(1, 1);                     PH_GO; MFMA16(0); PH_END;
        READ_A2(1, 1);                     PH_GO; MFMA16(4);
        __builtin_amdgcn_s_setprio(0);
    }
    __syncthreads();

    // ---------- LDS-staged vectorized epilogue ----------
    // C/D 16x16 layout: col = lane&15, row = (lane>>4)*4 + r.
    // Stagger: column 16-block XOR'd by ((rl>>2)&1)*16 to keep the scatter 2-way.
    int ci = cip[0];
    float wf = wfinP[b];
    const float* resid = lo + (((size_t)ci * BATCH + b) * SEQ + s0) * HID;
    float* op = out + ((size_t)b * SEQ + s0) * HID;
    float* ldsf = reinterpret_cast<float*>(ldsu);

    int rl16 = tid >> 4;          // 0..31
    int c16 = tid & 15;

    #pragma unroll 1
    for (int chunk = 0; chunk < 2; ++chunk) {
        if (wm == chunk) {
            #pragma unroll
            for (int m = 0; m < 8; ++m) {
                int rbase = m * 16 + (lane >> 4) * 4;
                #pragma unroll
                for (int n = 0; n < 4; ++n) {
                    int col64 = n * 16 + (lane & 15);
                    #pragma unroll
                    for (int r = 0; r < 4; ++r) {
                        int rl = rbase + r;
                        int colw = wn * 64 + (col64 ^ (((rl >> 2) & 1) << 4));
                        ldsf[rl * 256 + colw] = acc[m][n][r];
                    }
                }
            }
        }
        __syncthreads();
        #pragma unroll
        for (int p = 0; p < 4; ++p) {
            int rloc = p * 32 + rl16;
            int stag = ((rloc >> 2) & 1) << 4;
            int grow = chunk * 128 + rloc;
            const float* rrow = resid + (size_t)grow * HID + n0;
            float* orow = op + (size_t)grow * HID + n0;
            const float* brow = biasb + b * HID + n0;
            const float* lrow = ldsf + rloc * 256;
            #pragma unroll
            for (int seg = 0; seg < 4; ++seg) {
                int cl = seg * 64 + c16 * 4;
                float4 v = *reinterpret_cast<const float4*>(lrow + (cl ^ stag));
                float4 bs = *reinterpret_cast<const float4*>(brow + cl);
                float4 rs = *reinterpret_cast<const float4*>(rrow + cl);
                float4 o;
                o.x = v.x * wf + bs.x + rs.x;
                o.y = v.y * wf + bs.y + rs.y;
                o.z = v.z * wf + bs.z + rs.z;
                o.w = v.w * wf + bs.w + rs.w;
                *reinterpret_cast<float4*>(orow + cl) = o;
            }
        }
        __syncthreads();
    }
}

// ---------------- fallback: round-2 128^2 gload_lds GEMM (proven) ----------------
#define BM 128
#define BN 128
#define BK 64
#define NT (KTOT / BK)    // 192

__global__ __launch_bounds__(256, 2) void gemm128_kernel(
    const float* __restrict__ lo, const ushortT* __restrict__ Abf,
    const ushortT* __restrict__ Btp, const float* __restrict__ ratioP,
    const float* __restrict__ wfinP, const float* __restrict__ biasb,
    const int* __restrict__ cip, float* __restrict__ out)
{
    __shared__ ushortT lA[2][BM * BK];
    __shared__ ushortT lB[2][BN * BK];
    int t = threadIdx.x;
    int bid = blockIdx.x;
    int xcd = bid & 7, local = bid >> 3;
    int by = xcd * 16 + (local >> 3);
    int bx = local & 7;
    int b = by >> 4;
    int s0 = (by & 15) << 7;
    int n0 = bx << 7;
    int wid = t >> 6, lane = t & 63;
    int wr = wid >> 1, wc = wid & 1;
    int m16 = lane & 15, kb = lane >> 4;
    int aBase[4], bBase[4], ldsBase[4];
    #pragma unroll
    for (int i = 0; i < 4; ++i) {
        int ci2 = i * 256 + t;
        int row = ci2 >> 3, c = ci2 & 7;
        int sw = c ^ (row & 7);
        aBase[i] = (s0 + row) * HID + sw * 8;
        bBase[i] = (n0 + row) * KTOT + sw * 8;
        ldsBase[i] = i * 2048 + wid * 512;
    }
    int aoff[4][2], boff[4][2];
    #pragma unroll
    for (int i = 0; i < 4; ++i) {
        int ra = wr * 64 + i * 16 + m16;
        int rb = wc * 64 + i * 16 + m16;
        #pragma unroll
        for (int kk = 0; kk < 2; ++kk) {
            aoff[i][kk] = ra * 64 + (((kb + 4 * kk) ^ (ra & 7)) * 8);
            boff[i][kk] = rb * 64 + (((kb + 4 * kk) ^ (rb & 7)) * 8);
        }
    }
    f32x4 acc[4][4];
    #pragma unroll
    for (int i = 0; i < 4; ++i)
        #pragma unroll
        for (int j = 0; j < 4; ++j)
            acc[i][j] = (f32x4){0.f, 0.f, 0.f, 0.f};
    auto stage = [&](int buf, int tk2) {
        int l = tk2 >> 4;
        const ushortT* aT = Abf + (size_t)(l * BATCH + b) * (SEQ * HID) + ((tk2 & 15) << 6);
        const ushortT* bT = Btp + ((size_t)tk2 << 6);
        ushortT* la = &lA[buf][0];
        ushortT* lb = &lB[buf][0];
        #pragma unroll
        for (int i = 0; i < 4; ++i)
            __builtin_amdgcn_global_load_lds(
                (const __attribute__((address_space(1))) void*)(aT + aBase[i]),
                (__attribute__((address_space(3))) void*)(la + ldsBase[i]), 16, 0, 0);
        #pragma unroll
        for (int i = 0; i < 4; ++i)
            __builtin_amdgcn_global_load_lds(
                (const __attribute__((address_space(1))) void*)(bT + bBase[i]),
                (__attribute__((address_space(3))) void*)(lb + ldsBase[i]), 16, 0, 0);
    };
    stage(0, 0);
    __syncthreads();
    for (int tk = 0; tk < NT; ++tk) {
        int cur = tk & 1;
        if (tk + 1 < NT) stage(cur ^ 1, tk + 1);
        bf16x8 av[4][2], bv[4][2];
        #pragma unroll
        for (int i = 0; i < 4; ++i) {
            av[i][0] = *reinterpret_cast<const bf16x8*>(&lA[cur][aoff[i][0]]);
            av[i][1] = *reinterpret_cast<const bf16x8*>(&lA[cur][aoff[i][1]]);
            bv[i][0] = *reinterpret_cast<const bf16x8*>(&lB[cur][boff[i][0]]);
            bv[i][1] = *reinterpret_cast<const bf16x8*>(&lB[cur][boff[i][1]]);
        }
        if ((tk & 15) == 0 && tk) {
            float rr = ratioP[b * 16 + (tk >> 4)];
            #pragma unroll
            for (int i = 0; i < 4; ++i)
                #pragma unroll
                for (int j = 0; j < 4; ++j)
                    acc[i][j] = acc[i][j] * rr;
        }
        #pragma unroll
        for (int kk = 0; kk < 2; ++kk)
            #pragma unroll
            for (int fm = 0; fm < 4; ++fm)
                #pragma unroll
                for (int fn = 0; fn < 4; ++fn)
                    acc[fm][fn] = MM(av[fm][kk], bv[fn][kk], acc[fm][fn]);
        __syncthreads();
    }
    int ci = cip[0];
    float wf = wfinP[b];
    const float* resid = lo + (((size_t)ci * BATCH + b) * SEQ + s0) * HID;
    float* op = out + ((size_t)b * SEQ + s0) * HID;
    #pragma unroll
    for (int fn = 0; fn < 4; ++fn) {
        int col = n0 + wc * 64 + fn * 16 + m16;
        float bs = biasb[b * HID + col];
        #pragma unroll
        for (int fm = 0; fm < 4; ++fm) {
            int rbase = wr * 64 + fm * 16 + kb * 4;
            #pragma unroll
            for (int r = 0; r < 4; ++r) {
                float v = acc[fm][fn][r] * wf + bs + resid[(size_t)(rbase + r) * HID + col];
                op[(size_t)(rbase + r) * HID + col] = v;
            }
        }
    }
}

extern "C" void kernel_launch(void* const* d_in, const int* in_sizes, int n_in,
                              void* d_out, int out_size, void* d_ws, size_t ws_size,
                              hipStream_t stream) {
    const float* lo  = (const float*)d_in[0];
    const float* cw  = (const float*)d_in[1];
    const float* mU  = (const float*)d_in[2];
    const float* mV  = (const float*)d_in[3];
    const float* W1  = (const float*)d_in[4];
    const float* b1  = (const float*)d_in[5];
    const float* lnw = (const float*)d_in[6];
    const float* lnb = (const float*)d_in[7];
    const float* W2  = (const float*)d_in[8];
    const float* b2  = (const float*)d_in[9];
    const float* pW  = (const float*)d_in[10];
    const float* pb  = (const float*)d_in[11];
    const int*   ci  = (const int*)d_in[12];
    float* out = (float*)d_out;

    float* pooled = (float*)d_ws;                          // 98304 f
    float* gateb  = pooled + 98304;
    float* wsc    = gateb + 96;
    float* ratio  = wsc + 96;
    float* wfin   = ratio + 128;
    float* biasb  = wfin + 8;
    ushortT* Btp  = (ushortT*)((char*)d_ws + 458752);      // 25165824 B
    ushortT* Abf  = (ushortT*)((char*)d_ws + 25624576);    // 402653184 B
    const size_t need = 25624576ULL + 402653184ULL;

    int fast = (ws_size >= need) ? 1 : 0;

    hipMemsetAsync(pooled, 0, 98304 * sizeof(float), stream);
    streams_kernel<<<dim3(1536 + 3072), 256, 0, stream>>>(lo, pooled, Abf, fast, pW, Btp);
    gate_kernel<<<96, 256, 0, stream>>>(pooled, W1, b1, lnw, lnb, W2, b2, gateb);
    prep_kernel<<<1, 256, 0, stream>>>(cw, mU, mV, gateb, pb, ci, wsc, ratio, wfin, biasb);
    if (fast) {
        gemm8_kernel<<<dim3(256), 512, 0, stream>>>(lo, Abf, Btp, ratio, wfin, biasb, ci, out);
    } else {
        gemm128_kernel<<<dim3(1024), 256, 0, stream>>>(lo, Abf, Btp, ratio, wfin, biasb, ci, out);
    }
}

// Round 10
// 656.198 us; speedup vs baseline: 1.0231x; 1.0028x over previous
//
#include <hip/hip_runtime.h>
#include <hip/hip_bf16.h>
#include <math.h>

#define L_LAYERS 12
#define BATCH 8
#define SEQ 2048
#define HID 1024
#define DGATE 256
#define KTOT (L_LAYERS * HID)   // 12288
#define MTOT (BATCH * SEQ)      // 16384

typedef __attribute__((ext_vector_type(4))) float f32x4;
typedef __attribute__((ext_vector_type(8))) short bf16x8;
typedef unsigned short ushortT;

static __device__ __forceinline__ unsigned short f2bf(float x) {
    __hip_bfloat16 h = __float2bfloat16(x);
    return *reinterpret_cast<unsigned short*>(&h);
}

// ---------------- merged: pool(+bf16 convert of A) and transB ----------------
__global__ void streams_kernel(const float* __restrict__ lo, float* __restrict__ pooled,
                               ushortT* __restrict__ Abf, int doConv,
                               const float* __restrict__ W, ushortT* __restrict__ Bt) {
    __shared__ ushortT tile[64][72];
    int bid = blockIdx.x;
    int t = threadIdx.x;
    if (bid < 1536) {
        int lb = bid % 96;
        int sc = bid / 96;
        const float4* src = reinterpret_cast<const float4*>(lo + (size_t)lb * SEQ * HID);
        ushortT* dstb = Abf + (size_t)lb * SEQ * HID;
        float4 acc = {0.f, 0.f, 0.f, 0.f};
        int s0 = sc * 128;
        if (doConv) {
            #pragma unroll 4
            for (int s = s0; s < s0 + 128; ++s) {
                float4 v = src[(size_t)s * 256 + t];
                acc.x += v.x; acc.y += v.y; acc.z += v.z; acc.w += v.w;
                unsigned int u0 = (unsigned int)f2bf(v.x) | ((unsigned int)f2bf(v.y) << 16);
                unsigned int u1 = (unsigned int)f2bf(v.z) | ((unsigned int)f2bf(v.w) << 16);
                uint2 uu = {u0, u1};
                *reinterpret_cast<uint2*>(dstb + (size_t)s * HID + t * 4) = uu;
            }
        } else {
            #pragma unroll 4
            for (int s = s0; s < s0 + 128; ++s) {
                float4 v = src[(size_t)s * 256 + t];
                acc.x += v.x; acc.y += v.y; acc.z += v.z; acc.w += v.w;
            }
        }
        float* dst = pooled + (size_t)lb * HID + t * 4;
        atomicAdd(dst + 0, acc.x);
        atomicAdd(dst + 1, acc.y);
        atomicAdd(dst + 2, acc.z);
        atomicAdd(dst + 3, acc.w);
    } else {
        int idx = bid - 1536;
        int k0 = (idx % 192) * 64, n0 = (idx / 192) * 64;
        #pragma unroll
        for (int p = 0; p < 4; ++p) {
            int r = (t >> 4) + p * 16;
            int c = (t & 15) * 4;
            float4 v = *reinterpret_cast<const float4*>(W + (size_t)(k0 + r) * HID + n0 + c);
            tile[c + 0][r] = f2bf(v.x);
            tile[c + 1][r] = f2bf(v.y);
            tile[c + 2][r] = f2bf(v.z);
            tile[c + 3][r] = f2bf(v.w);
        }
        __syncthreads();
        #pragma unroll
        for (int p = 0; p < 2; ++p) {
            int idx2 = t + p * 256;
            int nl = idx2 >> 3;
            int kc = (idx2 & 7) * 8;
            uint4 v = *reinterpret_cast<const uint4*>(&tile[nl][kc]);
            *reinterpret_cast<uint4*>(Bt + (size_t)(n0 + nl) * KTOT + k0 + kc) = v;
        }
    }
}

// ---------------- gate MLP: one block per (l,b) ----------------
__global__ void gate_kernel(const float* __restrict__ pooled, const float* __restrict__ W1,
                            const float* __restrict__ b1, const float* __restrict__ lnw,
                            const float* __restrict__ lnb, const float* __restrict__ W2,
                            const float* __restrict__ b2, float* __restrict__ gate) {
    int lb = blockIdx.x;
    int l = lb >> 3;
    __shared__ float sp[HID];
    __shared__ float red[256];
    __shared__ float stat[2];
    int t = threadIdx.x;
    for (int i = t; i < HID; i += 256) sp[i] = pooled[(size_t)lb * HID + i] * (1.0f / 2048.0f);
    __syncthreads();
    const float* w1 = W1 + (size_t)l * HID * DGATE + t;
    float h = b1[l * DGATE + t];
    #pragma unroll 8
    for (int hh = 0; hh < HID; ++hh) h = fmaf(sp[hh], w1[(size_t)hh * DGATE], h);
    red[t] = h; __syncthreads();
    for (int o = 128; o > 0; o >>= 1) { if (t < o) red[t] += red[t + o]; __syncthreads(); }
    if (t == 0) stat[0] = red[0] * (1.0f / 256.0f);
    __syncthreads();
    float mu = stat[0];
    float c = h - mu;
    red[t] = c * c; __syncthreads();
    for (int o = 128; o > 0; o >>= 1) { if (t < o) red[t] += red[t + o]; __syncthreads(); }
    if (t == 0) stat[1] = red[0] * (1.0f / 256.0f);
    __syncthreads();
    float hn = c * rsqrtf(stat[1] + 1e-5f) * lnw[l * DGATE + t] + lnb[l * DGATE + t];
    float hg = hn * 0.5f * (1.0f + erff(hn * 0.70710678118654752f));
    red[t] = hg * W2[l * DGATE + t]; __syncthreads();
    for (int o = 128; o > 0; o >>= 1) { if (t < o) red[t] += red[t + o]; __syncthreads(); }
    if (t == 0) gate[lb] = 1.0f / (1.0f + expf(-(red[0] + b2[l])));
}

// ---------------- prep: m, w, ratios (Horner), bias ----------------
__global__ void prep_kernel(const float* __restrict__ cw, const float* __restrict__ U,
                            const float* __restrict__ V, const float* __restrict__ gate,
                            const float* __restrict__ projb, const int* __restrict__ cip,
                            float* __restrict__ wscale, float* __restrict__ ratio,
                            float* __restrict__ wfin, float* __restrict__ bias) {
    __shared__ float sm[L_LAYERS];
    __shared__ float sw[L_LAYERS * BATCH];
    int t = threadIdx.x;
    int ci = cip[0];
    if (t == 0) {
        float m[L_LAYERS];
        for (int i = 0; i < L_LAYERS; ++i) {
            float mm = cw[ci * L_LAYERS + i];
            float man = 0.f;
            for (int j = 0; j < 32; ++j) man = fmaf(U[ci * 32 + j], V[j * L_LAYERS + i], man);
            m[i] = 0.5f * mm + 0.5f * man;
        }
        for (int rep = 0; rep < 2; ++rep) {
            float mx = -1e30f;
            for (int i = 0; i < L_LAYERS; ++i) mx = fmaxf(mx, m[i]);
            float s = 0.f;
            for (int i = 0; i < L_LAYERS; ++i) { m[i] = expf(m[i] - mx); s += m[i]; }
            float inv = 1.0f / s;
            for (int i = 0; i < L_LAYERS; ++i) m[i] *= inv;
        }
        for (int i = 0; i < L_LAYERS; ++i) sm[i] = m[i];
    }
    __syncthreads();
    if (t < L_LAYERS * BATCH) {
        int l = t >> 3;
        float w = 0.9f * sm[l] * gate[t];
        sw[t] = w;
        wscale[t] = w;
    }
    __syncthreads();
    if (t < BATCH) {
        for (int l = 0; l < L_LAYERS; ++l) {
            float r = (l == 0) ? 1.0f : (sw[(l - 1) * BATCH + t] / sw[l * BATCH + t]);
            ratio[t * 16 + l] = r;
        }
        wfin[t] = sw[(L_LAYERS - 1) * BATCH + t];
    }
    for (int i = t; i < BATCH * HID; i += 256) {
        int b = i >> 10, k = i & 1023;
        float acc = 0.f;
        for (int l = 0; l < L_LAYERS; ++l) acc = fmaf(sw[l * BATCH + b], projb[l * HID + k], acc);
        bias[i] = acc;
    }
}

// ===== 256x256 GEMM, 16x16x32 MFMA, [256][64]+XOR(row&7), 4 barriers per 2-tile iteration =====

#define MM(a, bb, c) __builtin_amdgcn_mfma_f32_16x16x32_bf16(a, bb, c, 0, 0, 0)

#define LDSA(d, off) (*(const bf16x8*)(ldsu + (d) * 16384 + (off)))
#define LDSB(d, off) (*(const bf16x8*)(ldsu + 32768 + (d) * 16384 + (off)))

#define READ_AB(d, kk) { \
    av[0] = LDSA(d, aoff[0][kk]); av[1] = LDSA(d, aoff[1][kk]); \
    av[2] = LDSA(d, aoff[2][kk]); av[3] = LDSA(d, aoff[3][kk]); \
    bv[0] = LDSB(d, boff[0][kk]); bv[1] = LDSB(d, boff[1][kk]); \
    bv[2] = LDSB(d, boff[2][kk]); bv[3] = LDSB(d, boff[3][kk]); }

#define READ_A2(d, kk) { \
    av[0] = LDSA(d, aoff[4][kk]); av[1] = LDSA(d, aoff[5][kk]); \
    av[2] = LDSA(d, aoff[6][kk]); av[3] = LDSA(d, aoff[7][kk]); }

#define MFMA16(mb) { \
    acc[(mb)+0][0] = MM(av[0], bv[0], acc[(mb)+0][0]); acc[(mb)+0][1] = MM(av[0], bv[1], acc[(mb)+0][1]); \
    acc[(mb)+0][2] = MM(av[0], bv[2], acc[(mb)+0][2]); acc[(mb)+0][3] = MM(av[0], bv[3], acc[(mb)+0][3]); \
    acc[(mb)+1][0] = MM(av[1], bv[0], acc[(mb)+1][0]); acc[(mb)+1][1] = MM(av[1], bv[1], acc[(mb)+1][1]); \
    acc[(mb)+1][2] = MM(av[1], bv[2], acc[(mb)+1][2]); acc[(mb)+1][3] = MM(av[1], bv[3], acc[(mb)+1][3]); \
    acc[(mb)+2][0] = MM(av[2], bv[0], acc[(mb)+2][0]); acc[(mb)+2][1] = MM(av[2], bv[1], acc[(mb)+2][1]); \
    acc[(mb)+2][2] = MM(av[2], bv[2], acc[(mb)+2][2]); acc[(mb)+2][3] = MM(av[2], bv[3], acc[(mb)+2][3]); \
    acc[(mb)+3][0] = MM(av[3], bv[0], acc[(mb)+3][0]); acc[(mb)+3][1] = MM(av[3], bv[1], acc[(mb)+3][1]); \
    acc[(mb)+3][2] = MM(av[3], bv[2], acc[(mb)+3][2]); acc[(mb)+3][3] = MM(av[3], bv[3], acc[(mb)+3][3]); }

#define PGO   __builtin_amdgcn_s_setprio(1);
#define PSO   __builtin_amdgcn_s_setprio(0);
#define BARR  __builtin_amdgcn_s_barrier(); __builtin_amdgcn_sched_barrier(0);
#define BARRV(n) asm volatile("s_waitcnt vmcnt(" #n ")" ::: "memory"); \
    __builtin_amdgcn_s_barrier(); __builtin_amdgcn_sched_barrier(0);

__global__ __launch_bounds__(512, 2) void gemm8_kernel(
    const float* __restrict__ lo,
    const ushortT* __restrict__ Abf,          // bf16 A (L,B,S,H)
    const ushortT* __restrict__ Btp,          // bf16 Bt[n][k]
    const float* __restrict__ ratioP,         // [8][16]
    const float* __restrict__ wfinP,          // [8]
    const float* __restrict__ biasb,          // [8][1024]
    const int* __restrict__ cip,
    float* __restrict__ out)
{
    __shared__ ushortT ldsu[65536];           // 128 KiB

    const int tid = threadIdx.x;
    const int wid = tid >> 6, lane = tid & 63;
    const int wm = wid >> 2, wn = wid & 3;

    int bid = blockIdx.x;
    int xcd = bid & 7, local = bid >> 3;
    int mt = xcd * 8 + (local >> 2);          // 0..63
    int nt = local & 3;                       // 0..3
    int b = mt >> 3;
    int s0 = (mt & 7) << 8;
    int n0 = nt << 8;

    // staging: thread covers physical chunk (row=tid>>3, c=tid&7) of a 64-row block;
    // global source chunk = c ^ (row&7).
    const int csrc = (tid & 7) ^ ((tid >> 3) & 7);
    const size_t aRow = (size_t)(tid >> 3) * HID + csrc * 8;
    const size_t bRow = (size_t)(n0 + (tid >> 3)) * KTOT + csrc * 8;
    const int ldst = tid * 8;
    const ushortT* aPlane0 = Abf + (size_t)b * (SEQ * HID) + (size_t)s0 * HID;

    auto stageA = [&](int d, int h, int kt) {
        int l = kt >> 4;
        const ushortT* plane = aPlane0 + (size_t)l * (BATCH * SEQ * HID) + ((kt & 15) << 6);
        #pragma unroll
        for (int j = 0; j < 2; ++j) {
            const ushortT* src = plane + (size_t)(h * 128 + j * 64) * HID + aRow;
            ushortT* dst = ldsu + d * 16384 + (h * 128 + j * 64) * 64 + ldst;
            __builtin_amdgcn_global_load_lds(
                (const __attribute__((address_space(1))) void*)src,
                (__attribute__((address_space(3))) void*)dst, 16, 0, 0);
        }
    };
    auto stageB = [&](int d, int h, int kt) {
        const ushortT* baseB = Btp + ((size_t)kt << 6);
        #pragma unroll
        for (int j = 0; j < 2; ++j) {
            const ushortT* src = baseB + (size_t)(h * 128 + j * 64) * KTOT + bRow;
            ushortT* dst = ldsu + 32768 + d * 16384 + (h * 128 + j * 64) * 64 + ldst;
            __builtin_amdgcn_global_load_lds(
                (const __attribute__((address_space(1))) void*)src,
                (__attribute__((address_space(3))) void*)dst, 16, 0, 0);
        }
    };

    // fragment offsets: row = base + f*16 + (lane&15); logical chunk = kk*4 + (lane>>4);
    // physical chunk = logical ^ (row&7); row&7 == lane&7.
    int csw[2];
    {
        int kb = lane >> 4;
        csw[0] = ((kb + 0) ^ (lane & 7)) * 8;
        csw[1] = ((kb + 4) ^ (lane & 7)) * 8;
    }
    int aoff[8][2], boff[4][2];
    #pragma unroll
    for (int m = 0; m < 8; ++m) {
        int row = wm * 128 + m * 16 + (lane & 15);
        aoff[m][0] = row * 64 + csw[0];
        aoff[m][1] = row * 64 + csw[1];
    }
    #pragma unroll
    for (int n = 0; n < 4; ++n) {
        int row = wn * 64 + n * 16 + (lane & 15);
        boff[n][0] = row * 64 + csw[0];
        boff[n][1] = row * 64 + csw[1];
    }

    f32x4 acc[8][4];
    #pragma unroll
    for (int m = 0; m < 8; ++m)
        #pragma unroll
        for (int n = 0; n < 4; ++n)
            acc[m][n] = (f32x4){0.f, 0.f, 0.f, 0.f};

    // prologue: A0<-t0 (4), B0<-t0 (4), B1<-t1 (4); first 8 must land.
    stageA(0, 0, 0); stageA(0, 1, 0);
    stageB(0, 0, 0); stageB(0, 1, 0);
    stageB(1, 0, 1); stageB(1, 1, 1);
    asm volatile("s_waitcnt vmcnt(4)" ::: "memory");
    __builtin_amdgcn_s_barrier();
    __builtin_amdgcn_sched_barrier(0);

    bf16x8 av[4], bv[4];

    #pragma unroll 1
    for (int i = 0; i < 95; ++i) {
        int t1 = 2 * i + 1;
        if (i && !(i & 7)) {                  // entering a new layer: Horner rescale
            float rr = ratioP[b * 16 + (i >> 3)];
            #pragma unroll
            for (int m = 0; m < 8; ++m)
                #pragma unroll
                for (int n = 0; n < 4; ++n)
                    acc[m][n] *= rr;
        }
        // ---- region 1: P1-P3 (no intermediate barriers; waves may skew) ----
        READ_AB(0, 0); stageA(1, 0, t1);                           PGO; MFMA16(0); PSO;
        READ_A2(0, 0); stageA(1, 1, t1);                           PGO; MFMA16(4); PSO;
        READ_AB(0, 1);                                             PGO; MFMA16(0); PSO;
        BARR;                                 // all waves done reading buf0-B
        // ---- P4: stage B0 <- t0+2; vmcnt(4) drains prev-B1 + A1 ----
        READ_A2(0, 1); stageB(0, 0, t1 + 1); stageB(0, 1, t1 + 1); PGO; MFMA16(4); PSO;
        BARRV(4);
        // ---- region 2: P5-P7 ----
        READ_AB(1, 0); stageA(0, 0, t1 + 1);                       PGO; MFMA16(0); PSO;
        READ_A2(1, 0); stageA(0, 1, t1 + 1);                       PGO; MFMA16(4); PSO;
        READ_AB(1, 1);                                             PGO; MFMA16(0); PSO;
        BARR;                                 // all waves done reading buf1-B
        // ---- P8: stage B1 <- t1+2; vmcnt(4) drains B0 + A0 ----
        READ_A2(1, 1); stageB(1, 0, t1 + 2); stageB(1, 1, t1 + 2); PGO; MFMA16(4); PSO;
        BARRV(4);
    }

    // final iteration (t0=190 in buf0, t1=191 in buf1)
    {
        READ_AB(0, 0); stageA(1, 0, 191);  PGO; MFMA16(0); PSO;
        READ_A2(0, 0); stageA(1, 1, 191);  PGO; MFMA16(4); PSO;
        READ_AB(0, 1);                     PGO; MFMA16(0); PSO;
        BARR;
        READ_A2(0, 1);                     PGO; MFMA16(4); PSO;
        BARRV(0);
        READ_AB(1, 0);                     PGO; MFMA16(0); PSO;
        READ_A2(1, 0);                     PGO; MFMA16(4); PSO;
        READ_AB(1, 1);                     PGO; MFMA16(0); PSO;
        READ_A2(1, 1);                     PGO; MFMA16(4); PSO;
    }
    __syncthreads();

    // ---------- LDS-staged vectorized epilogue ----------
    // C/D 16x16 layout: col = lane&15, row = (lane>>4)*4 + r.
    int ci = cip[0];
    float wf = wfinP[b];
    const float* resid = lo + (((size_t)ci * BATCH + b) * SEQ + s0) * HID;
    float* op = out + ((size_t)b * SEQ + s0) * HID;
    float* ldsf = reinterpret_cast<float*>(ldsu);

    int rl16 = tid >> 4;          // 0..31
    int c16 = tid & 15;

    #pragma unroll 1
    for (int chunk = 0; chunk < 2; ++chunk) {
        if (wm == chunk) {
            #pragma unroll
            for (int m = 0; m < 8; ++m) {
                int rbase = m * 16 + (lane >> 4) * 4;
                #pragma unroll
                for (int n = 0; n < 4; ++n) {
                    int col64 = n * 16 + (lane & 15);
                    #pragma unroll
                    for (int r = 0; r < 4; ++r) {
                        int rl = rbase + r;
                        int colw = wn * 64 + (col64 ^ (((rl >> 2) & 1) << 4));
                        ldsf[rl * 256 + colw] = acc[m][n][r];
                    }
                }
            }
        }
        __syncthreads();
        #pragma unroll
        for (int p = 0; p < 4; ++p) {
            int rloc = p * 32 + rl16;
            int stag = ((rloc >> 2) & 1) << 4;
            int grow = chunk * 128 + rloc;
            const float* rrow = resid + (size_t)grow * HID + n0;
            float* orow = op + (size_t)grow * HID + n0;
            const float* brow = biasb + b * HID + n0;
            const float* lrow = ldsf + rloc * 256;
            #pragma unroll
            for (int seg = 0; seg < 4; ++seg) {
                int cl = seg * 64 + c16 * 4;
                float4 v = *reinterpret_cast<const float4*>(lrow + (cl ^ stag));
                float4 bs = *reinterpret_cast<const float4*>(brow + cl);
                float4 rs = *reinterpret_cast<const float4*>(rrow + cl);
                float4 o;
                o.x = v.x * wf + bs.x + rs.x;
                o.y = v.y * wf + bs.y + rs.y;
                o.z = v.z * wf + bs.z + rs.z;
                o.w = v.w * wf + bs.w + rs.w;
                *reinterpret_cast<float4*>(orow + cl) = o;
            }
        }
        __syncthreads();
    }
}

// ---------------- fallback: round-2 128^2 gload_lds GEMM (proven) ----------------
#define BM 128
#define BN 128
#define BK 64
#define NT (KTOT / BK)    // 192

__global__ __launch_bounds__(256, 2) void gemm128_kernel(
    const float* __restrict__ lo, const ushortT* __restrict__ Abf,
    const ushortT* __restrict__ Btp, const float* __restrict__ ratioP,
    const float* __restrict__ wfinP, const float* __restrict__ biasb,
    const int* __restrict__ cip, float* __restrict__ out)
{
    __shared__ ushortT lA[2][BM * BK];
    __shared__ ushortT lB[2][BN * BK];
    int t = threadIdx.x;
    int bid = blockIdx.x;
    int xcd = bid & 7, local = bid >> 3;
    int by = xcd * 16 + (local >> 3);
    int bx = local & 7;
    int b = by >> 4;
    int s0 = (by & 15) << 7;
    int n0 = bx << 7;
    int wid = t >> 6, lane = t & 63;
    int wr = wid >> 1, wc = wid & 1;
    int m16 = lane & 15, kb = lane >> 4;
    int aBase[4], bBase[4], ldsBase[4];
    #pragma unroll
    for (int i = 0; i < 4; ++i) {
        int ci2 = i * 256 + t;
        int row = ci2 >> 3, c = ci2 & 7;
        int sw = c ^ (row & 7);
        aBase[i] = (s0 + row) * HID + sw * 8;
        bBase[i] = (n0 + row) * KTOT + sw * 8;
        ldsBase[i] = i * 2048 + wid * 512;
    }
    int aoff[4][2], boff[4][2];
    #pragma unroll
    for (int i = 0; i < 4; ++i) {
        int ra = wr * 64 + i * 16 + m16;
        int rb = wc * 64 + i * 16 + m16;
        #pragma unroll
        for (int kk = 0; kk < 2; ++kk) {
            aoff[i][kk] = ra * 64 + (((kb + 4 * kk) ^ (ra & 7)) * 8);
            boff[i][kk] = rb * 64 + (((kb + 4 * kk) ^ (rb & 7)) * 8);
        }
    }
    f32x4 acc[4][4];
    #pragma unroll
    for (int i = 0; i < 4; ++i)
        #pragma unroll
        for (int j = 0; j < 4; ++j)
            acc[i][j] = (f32x4){0.f, 0.f, 0.f, 0.f};
    auto stage = [&](int buf, int tk2) {
        int l = tk2 >> 4;
        const ushortT* aT = Abf + (size_t)(l * BATCH + b) * (SEQ * HID) + ((tk2 & 15) << 6);
        const ushortT* bT = Btp + ((size_t)tk2 << 6);
        ushortT* la = &lA[buf][0];
        ushortT* lb = &lB[buf][0];
        #pragma unroll
        for (int i = 0; i < 4; ++i)
            __builtin_amdgcn_global_load_lds(
                (const __attribute__((address_space(1))) void*)(aT + aBase[i]),
                (__attribute__((address_space(3))) void*)(la + ldsBase[i]), 16, 0, 0);
        #pragma unroll
        for (int i = 0; i < 4; ++i)
            __builtin_amdgcn_global_load_lds(
                (const __attribute__((address_space(1))) void*)(bT + bBase[i]),
                (__attribute__((address_space(3))) void*)(lb + ldsBase[i]), 16, 0, 0);
    };
    stage(0, 0);
    __syncthreads();
    for (int tk = 0; tk < NT; ++tk) {
        int cur = tk & 1;
        if (tk + 1 < NT) stage(cur ^ 1, tk + 1);
        bf16x8 av[4][2], bv[4][2];
        #pragma unroll
        for (int i = 0; i < 4; ++i) {
            av[i][0] = *reinterpret_cast<const bf16x8*>(&lA[cur][aoff[i][0]]);
            av[i][1] = *reinterpret_cast<const bf16x8*>(&lA[cur][aoff[i][1]]);
            bv[i][0] = *reinterpret_cast<const bf16x8*>(&lB[cur][boff[i][0]]);
            bv[i][1] = *reinterpret_cast<const bf16x8*>(&lB[cur][boff[i][1]]);
        }
        if ((tk & 15) == 0 && tk) {
            float rr = ratioP[b * 16 + (tk >> 4)];
            #pragma unroll
            for (int i = 0; i < 4; ++i)
                #pragma unroll
                for (int j = 0; j < 4; ++j)
                    acc[i][j] = acc[i][j] * rr;
        }
        #pragma unroll
        for (int kk = 0; kk < 2; ++kk)
            #pragma unroll
            for (int fm = 0; fm < 4; ++fm)
                #pragma unroll
                for (int fn = 0; fn < 4; ++fn)
                    acc[fm][fn] = MM(av[fm][kk], bv[fn][kk], acc[fm][fn]);
        __syncthreads();
    }
    int ci = cip[0];
    float wf = wfinP[b];
    const float* resid = lo + (((size_t)ci * BATCH + b) * SEQ + s0) * HID;
    float* op = out + ((size_t)b * SEQ + s0) * HID;
    #pragma unroll
    for (int fn = 0; fn < 4; ++fn) {
        int col = n0 + wc * 64 + fn * 16 + m16;
        float bs = biasb[b * HID + col];
        #pragma unroll
        for (int fm = 0; fm < 4; ++fm) {
            int rbase = wr * 64 + fm * 16 + kb * 4;
            #pragma unroll
            for (int r = 0; r < 4; ++r) {
                float v = acc[fm][fn][r] * wf + bs + resid[(size_t)(rbase + r) * HID + col];
                op[(size_t)(rbase + r) * HID + col] = v;
            }
        }
    }
}

extern "C" void kernel_launch(void* const* d_in, const int* in_sizes, int n_in,
                              void* d_out, int out_size, void* d_ws, size_t ws_size,
                              hipStream_t stream) {
    const float* lo  = (const float*)d_in[0];
    const float* cw  = (const float*)d_in[1];
    const float* mU  = (const float*)d_in[2];
    const float* mV  = (const float*)d_in[3];
    const float* W1  = (const float*)d_in[4];
    const float* b1  = (const float*)d_in[5];
    const float* lnw = (const float*)d_in[6];
    const float* lnb = (const float*)d_in[7];
    const float* W2  = (const float*)d_in[8];
    const float* b2  = (const float*)d_in[9];
    const float* pW  = (const float*)d_in[10];
    const float* pb  = (const float*)d_in[11];
    const int*   ci  = (const int*)d_in[12];
    float* out = (float*)d_out;

    float* pooled = (float*)d_ws;                          // 98304 f
    float* gateb  = pooled + 98304;
    float* wsc    = gateb + 96;
    float* ratio  = wsc + 96;
    float* wfin   = ratio + 128;
    float* biasb  = wfin + 8;
    ushortT* Btp  = (ushortT*)((char*)d_ws + 458752);      // 25165824 B
    ushortT* Abf  = (ushortT*)((char*)d_ws + 25624576);    // 402653184 B
    const size_t need = 25624576ULL + 402653184ULL;

    int fast = (ws_size >= need) ? 1 : 0;

    hipMemsetAsync(pooled, 0, 98304 * sizeof(float), stream);
    streams_kernel<<<dim3(1536 + 3072), 256, 0, stream>>>(lo, pooled, Abf, fast, pW, Btp);
    gate_kernel<<<96, 256, 0, stream>>>(pooled, W1, b1, lnw, lnb, W2, b2, gateb);
    prep_kernel<<<1, 256, 0, stream>>>(cw, mU, mV, gateb, pb, ci, wsc, ratio, wfin, biasb);
    if (fast) {
        gemm8_kernel<<<dim3(256), 512, 0, stream>>>(lo, Abf, Btp, ratio, wfin, biasb, ci, out);
    } else {
        gemm128_kernel<<<dim3(1024), 256, 0, stream>>>(lo, Abf, Btp, ratio, wfin, biasb, ci, out);
    }
}

// Round 11
// 653.154 us; speedup vs baseline: 1.0279x; 1.0047x over previous
//
#include <hip/hip_runtime.h>
#include <hip/hip_bf16.h>
#include <math.h>

#define L_LAYERS 12
#define BATCH 8
#define SEQ 2048
#define HID 1024
#define DGATE 256
#define KTOT (L_LAYERS * HID)   // 12288
#define MTOT (BATCH * SEQ)      // 16384

typedef __attribute__((ext_vector_type(4))) float f32x4;
typedef __attribute__((ext_vector_type(8))) short bf16x8;
typedef unsigned short ushortT;

static __device__ __forceinline__ unsigned short f2bf(float x) {
    __hip_bfloat16 h = __float2bfloat16(x);
    return *reinterpret_cast<unsigned short*>(&h);
}

// ---------------- merged: pool(+bf16 convert of A) and transB ----------------
__global__ void streams_kernel(const float* __restrict__ lo, float* __restrict__ pooled,
                               ushortT* __restrict__ Abf, int doConv,
                               const float* __restrict__ W, ushortT* __restrict__ Bt) {
    __shared__ ushortT tile[64][72];
    int bid = blockIdx.x;
    int t = threadIdx.x;
    if (bid < 1536) {
        int lb = bid % 96;
        int sc = bid / 96;
        const float4* src = reinterpret_cast<const float4*>(lo + (size_t)lb * SEQ * HID);
        ushortT* dstb = Abf + (size_t)lb * SEQ * HID;
        float4 acc = {0.f, 0.f, 0.f, 0.f};
        int s0 = sc * 128;
        if (doConv) {
            #pragma unroll 4
            for (int s = s0; s < s0 + 128; ++s) {
                float4 v = src[(size_t)s * 256 + t];
                acc.x += v.x; acc.y += v.y; acc.z += v.z; acc.w += v.w;
                unsigned int u0 = (unsigned int)f2bf(v.x) | ((unsigned int)f2bf(v.y) << 16);
                unsigned int u1 = (unsigned int)f2bf(v.z) | ((unsigned int)f2bf(v.w) << 16);
                uint2 uu = {u0, u1};
                *reinterpret_cast<uint2*>(dstb + (size_t)s * HID + t * 4) = uu;
            }
        } else {
            #pragma unroll 4
            for (int s = s0; s < s0 + 128; ++s) {
                float4 v = src[(size_t)s * 256 + t];
                acc.x += v.x; acc.y += v.y; acc.z += v.z; acc.w += v.w;
            }
        }
        float* dst = pooled + (size_t)lb * HID + t * 4;
        atomicAdd(dst + 0, acc.x);
        atomicAdd(dst + 1, acc.y);
        atomicAdd(dst + 2, acc.z);
        atomicAdd(dst + 3, acc.w);
    } else {
        int idx = bid - 1536;
        int k0 = (idx % 192) * 64, n0 = (idx / 192) * 64;
        #pragma unroll
        for (int p = 0; p < 4; ++p) {
            int r = (t >> 4) + p * 16;
            int c = (t & 15) * 4;
            float4 v = *reinterpret_cast<const float4*>(W + (size_t)(k0 + r) * HID + n0 + c);
            tile[c + 0][r] = f2bf(v.x);
            tile[c + 1][r] = f2bf(v.y);
            tile[c + 2][r] = f2bf(v.z);
            tile[c + 3][r] = f2bf(v.w);
        }
        __syncthreads();
        #pragma unroll
        for (int p = 0; p < 2; ++p) {
            int idx2 = t + p * 256;
            int nl = idx2 >> 3;
            int kc = (idx2 & 7) * 8;
            uint4 v = *reinterpret_cast<const uint4*>(&tile[nl][kc]);
            *reinterpret_cast<uint4*>(Bt + (size_t)(n0 + nl) * KTOT + k0 + kc) = v;
        }
    }
}

// ---------------- gate MLP: one block per (l,b) ----------------
__global__ void gate_kernel(const float* __restrict__ pooled, const float* __restrict__ W1,
                            const float* __restrict__ b1, const float* __restrict__ lnw,
                            const float* __restrict__ lnb, const float* __restrict__ W2,
                            const float* __restrict__ b2, float* __restrict__ gate) {
    int lb = blockIdx.x;
    int l = lb >> 3;
    __shared__ float sp[HID];
    __shared__ float red[256];
    __shared__ float stat[2];
    int t = threadIdx.x;
    for (int i = t; i < HID; i += 256) sp[i] = pooled[(size_t)lb * HID + i] * (1.0f / 2048.0f);
    __syncthreads();
    const float* w1 = W1 + (size_t)l * HID * DGATE + t;
    float h = b1[l * DGATE + t];
    #pragma unroll 8
    for (int hh = 0; hh < HID; ++hh) h = fmaf(sp[hh], w1[(size_t)hh * DGATE], h);
    red[t] = h; __syncthreads();
    for (int o = 128; o > 0; o >>= 1) { if (t < o) red[t] += red[t + o]; __syncthreads(); }
    if (t == 0) stat[0] = red[0] * (1.0f / 256.0f);
    __syncthreads();
    float mu = stat[0];
    float c = h - mu;
    red[t] = c * c; __syncthreads();
    for (int o = 128; o > 0; o >>= 1) { if (t < o) red[t] += red[t + o]; __syncthreads(); }
    if (t == 0) stat[1] = red[0] * (1.0f / 256.0f);
    __syncthreads();
    float hn = c * rsqrtf(stat[1] + 1e-5f) * lnw[l * DGATE + t] + lnb[l * DGATE + t];
    float hg = hn * 0.5f * (1.0f + erff(hn * 0.70710678118654752f));
    red[t] = hg * W2[l * DGATE + t]; __syncthreads();
    for (int o = 128; o > 0; o >>= 1) { if (t < o) red[t] += red[t + o]; __syncthreads(); }
    if (t == 0) gate[lb] = 1.0f / (1.0f + expf(-(red[0] + b2[l])));
}

// ---------------- prep: m, w, ratios (Horner), bias ----------------
__global__ void prep_kernel(const float* __restrict__ cw, const float* __restrict__ U,
                            const float* __restrict__ V, const float* __restrict__ gate,
                            const float* __restrict__ projb, const int* __restrict__ cip,
                            float* __restrict__ wscale, float* __restrict__ ratio,
                            float* __restrict__ wfin, float* __restrict__ bias) {
    __shared__ float sm[L_LAYERS];
    __shared__ float sw[L_LAYERS * BATCH];
    int t = threadIdx.x;
    int ci = cip[0];
    if (t == 0) {
        float m[L_LAYERS];
        for (int i = 0; i < L_LAYERS; ++i) {
            float mm = cw[ci * L_LAYERS + i];
            float man = 0.f;
            for (int j = 0; j < 32; ++j) man = fmaf(U[ci * 32 + j], V[j * L_LAYERS + i], man);
            m[i] = 0.5f * mm + 0.5f * man;
        }
        for (int rep = 0; rep < 2; ++rep) {
            float mx = -1e30f;
            for (int i = 0; i < L_LAYERS; ++i) mx = fmaxf(mx, m[i]);
            float s = 0.f;
            for (int i = 0; i < L_LAYERS; ++i) { m[i] = expf(m[i] - mx); s += m[i]; }
            float inv = 1.0f / s;
            for (int i = 0; i < L_LAYERS; ++i) m[i] *= inv;
        }
        for (int i = 0; i < L_LAYERS; ++i) sm[i] = m[i];
    }
    __syncthreads();
    if (t < L_LAYERS * BATCH) {
        int l = t >> 3;
        float w = 0.9f * sm[l] * gate[t];
        sw[t] = w;
        wscale[t] = w;
    }
    __syncthreads();
    if (t < BATCH) {
        for (int l = 0; l < L_LAYERS; ++l) {
            float r = (l == 0) ? 1.0f : (sw[(l - 1) * BATCH + t] / sw[l * BATCH + t]);
            ratio[t * 16 + l] = r;
        }
        wfin[t] = sw[(L_LAYERS - 1) * BATCH + t];
    }
    for (int i = t; i < BATCH * HID; i += 256) {
        int b = i >> 10, k = i & 1023;
        float acc = 0.f;
        for (int l = 0; l < L_LAYERS; ++l) acc = fmaf(sw[l * BATCH + b], projb[l * HID + k], acc);
        bias[i] = acc;
    }
}

// ===== 256x256 GEMM, 16x16x32 MFMA, [256][64]+XOR(row&7), pre-read regs + 4 barriers/iter =====

#define MM(a, bb, c) __builtin_amdgcn_mfma_f32_16x16x32_bf16(a, bb, c, 0, 0, 0)

#define LDSA(d, off) (*(const bf16x8*)(ldsu + (d) * 16384 + (off)))
#define LDSB(d, off) (*(const bf16x8*)(ldsu + 32768 + (d) * 16384 + (off)))

// read A group g (rows 4g..4g+3 of wave's 8) k-half kk of buf d into dst[0..3]
#define RDA(dst, d, g, kk) { \
    dst[0] = LDSA(d, aK[kk] + ((g) * 4 + 0) * 1024); \
    dst[1] = LDSA(d, aK[kk] + ((g) * 4 + 1) * 1024); \
    dst[2] = LDSA(d, aK[kk] + ((g) * 4 + 2) * 1024); \
    dst[3] = LDSA(d, aK[kk] + ((g) * 4 + 3) * 1024); }

#define RDB(dst, d, kk) { \
    dst[0] = LDSB(d, bK[kk] + 0 * 1024); \
    dst[1] = LDSB(d, bK[kk] + 1 * 1024); \
    dst[2] = LDSB(d, bK[kk] + 2 * 1024); \
    dst[3] = LDSB(d, bK[kk] + 3 * 1024); }

#define MFMA16R(mb, A, B) { \
    acc[(mb)+0][0] = MM(A[0], B[0], acc[(mb)+0][0]); acc[(mb)+0][1] = MM(A[0], B[1], acc[(mb)+0][1]); \
    acc[(mb)+0][2] = MM(A[0], B[2], acc[(mb)+0][2]); acc[(mb)+0][3] = MM(A[0], B[3], acc[(mb)+0][3]); \
    acc[(mb)+1][0] = MM(A[1], B[0], acc[(mb)+1][0]); acc[(mb)+1][1] = MM(A[1], B[1], acc[(mb)+1][1]); \
    acc[(mb)+1][2] = MM(A[1], B[2], acc[(mb)+1][2]); acc[(mb)+1][3] = MM(A[1], B[3], acc[(mb)+1][3]); \
    acc[(mb)+2][0] = MM(A[2], B[0], acc[(mb)+2][0]); acc[(mb)+2][1] = MM(A[2], B[1], acc[(mb)+2][1]); \
    acc[(mb)+2][2] = MM(A[2], B[2], acc[(mb)+2][2]); acc[(mb)+2][3] = MM(A[2], B[3], acc[(mb)+2][3]); \
    acc[(mb)+3][0] = MM(A[3], B[0], acc[(mb)+3][0]); acc[(mb)+3][1] = MM(A[3], B[1], acc[(mb)+3][1]); \
    acc[(mb)+3][2] = MM(A[3], B[2], acc[(mb)+3][2]); acc[(mb)+3][3] = MM(A[3], B[3], acc[(mb)+3][3]); }

#define PGO   __builtin_amdgcn_s_setprio(1);
#define PSO   __builtin_amdgcn_s_setprio(0);
#define BARR  __builtin_amdgcn_s_barrier(); __builtin_amdgcn_sched_barrier(0);
#define BARRV(n) asm volatile("s_waitcnt vmcnt(" #n ")" ::: "memory"); \
    __builtin_amdgcn_s_barrier(); __builtin_amdgcn_sched_barrier(0);

__global__ __launch_bounds__(512, 2) void gemm8_kernel(
    const float* __restrict__ lo,
    const ushortT* __restrict__ Abf,          // bf16 A (L,B,S,H)
    const ushortT* __restrict__ Btp,          // bf16 Bt[n][k]
    const float* __restrict__ ratioP,         // [8][16]
    const float* __restrict__ wfinP,          // [8]
    const float* __restrict__ biasb,          // [8][1024]
    const int* __restrict__ cip,
    float* __restrict__ out)
{
    __shared__ ushortT ldsu[65536];           // 128 KiB

    const int tid = threadIdx.x;
    const int wid = tid >> 6, lane = tid & 63;
    const int wm = wid >> 2, wn = wid & 3;

    int bid = blockIdx.x;
    int xcd = bid & 7, local = bid >> 3;
    int mt = xcd * 8 + (local >> 2);          // 0..63
    int nt = local & 3;                       // 0..3
    int b = mt >> 3;
    int s0 = (mt & 7) << 8;
    int n0 = nt << 8;

    // staging: thread covers physical chunk (row=tid>>3, c=tid&7) of a 64-row block;
    // global source chunk = c ^ (row&7).
    const int csrc = (tid & 7) ^ ((tid >> 3) & 7);
    const size_t aRow = (size_t)(tid >> 3) * HID + csrc * 8;
    const size_t bRow = (size_t)(n0 + (tid >> 3)) * KTOT + csrc * 8;
    const int ldst = tid * 8;
    const ushortT* aPlane0 = Abf + (size_t)b * (SEQ * HID) + (size_t)s0 * HID;

    auto stageA = [&](int d, int h, int kt) {
        int l = kt >> 4;
        const ushortT* plane = aPlane0 + (size_t)l * (BATCH * SEQ * HID) + ((kt & 15) << 6);
        #pragma unroll
        for (int j = 0; j < 2; ++j) {
            const ushortT* src = plane + (size_t)(h * 128 + j * 64) * HID + aRow;
            ushortT* dst = ldsu + d * 16384 + (h * 128 + j * 64) * 64 + ldst;
            __builtin_amdgcn_global_load_lds(
                (const __attribute__((address_space(1))) void*)src,
                (__attribute__((address_space(3))) void*)dst, 16, 0, 0);
        }
    };
    auto stageB = [&](int d, int h, int kt) {
        const ushortT* baseB = Btp + ((size_t)kt << 6);
        #pragma unroll
        for (int j = 0; j < 2; ++j) {
            const ushortT* src = baseB + (size_t)(h * 128 + j * 64) * KTOT + bRow;
            ushortT* dst = ldsu + 32768 + d * 16384 + (h * 128 + j * 64) * 64 + ldst;
            __builtin_amdgcn_global_load_lds(
                (const __attribute__((address_space(1))) void*)src,
                (__attribute__((address_space(3))) void*)dst, 16, 0, 0);
        }
    };

    // fragment base offsets (ushorts). row = base + frag*16 + (lane&15); frag spacing = 1024.
    // logical chunk = kk*4 + (lane>>4); physical = logical ^ (row&7); row&7 == lane&7.
    int aK[2], bK[2];
    {
        int kb = lane >> 4;
        int c0 = ((kb + 0) ^ (lane & 7)) * 8;
        int c1 = ((kb + 4) ^ (lane & 7)) * 8;
        int ar = (wm * 128 + (lane & 15)) * 64;
        int br = (wn * 64 + (lane & 15)) * 64;
        aK[0] = ar + c0; aK[1] = ar + c1;
        bK[0] = br + c0; bK[1] = br + c1;
    }

    f32x4 acc[8][4];
    #pragma unroll
    for (int m = 0; m < 8; ++m)
        #pragma unroll
        for (int n = 0; n < 4; ++n)
            acc[m][n] = (f32x4){0.f, 0.f, 0.f, 0.f};

    // prologue: A0<-t0 (4), B0<-t0 (4), B1<-t1 (4); first 8 must land.
    stageA(0, 0, 0); stageA(0, 1, 0);
    stageB(0, 0, 0); stageB(0, 1, 0);
    stageB(1, 0, 1); stageB(1, 1, 1);
    asm volatile("s_waitcnt vmcnt(4)" ::: "memory");
    __builtin_amdgcn_s_barrier();
    __builtin_amdgcn_sched_barrier(0);

    bf16x8 avA[4], avB[4], bvA[4], bvB[4];

    #pragma unroll 1
    for (int i = 0; i < 95; ++i) {
        int t1 = 2 * i + 1;
        if (i && !(i & 7)) {                  // entering a new layer: Horner rescale
            float rr = ratioP[b * 16 + (i >> 3)];
            #pragma unroll
            for (int m = 0; m < 8; ++m)
                #pragma unroll
                for (int n = 0; n < 4; ++n)
                    acc[m][n] *= rr;
        }
        // ---- region 1: P1-P3 (reads pre-issued one phase ahead; no intermediate barriers) ----
        // P1: own frags + next phase's A
        RDA(avA, 0, 0, 0); RDB(bvA, 0, 0); RDA(avB, 0, 1, 0);
        stageA(1, 0, t1);
        PGO; MFMA16R(0, avA, bvA); PSO;
        // P2: pre-read P3's frags (A kk1 g0 + B kk1)
        RDA(avA, 0, 0, 1); RDB(bvB, 0, 1);
        stageA(1, 1, t1);
        PGO; MFMA16R(4, avB, bvA); PSO;
        // P3: pre-read P4's frags (A kk1 g1)
        RDA(avB, 0, 1, 1);
        PGO; MFMA16R(0, avA, bvB); PSO;
        BARR;                                 // all buf0-B reads drained by P3's MFMA
        // P4: stage B0 <- t0+2; MFMA from regs only; vmcnt(4) drains prev-B1 + A1
        stageB(0, 0, t1 + 1); stageB(0, 1, t1 + 1);
        PGO; MFMA16R(4, avB, bvB); PSO;
        BARRV(4);
        // ---- region 2: P5-P7 (buf1) ----
        RDA(avA, 1, 0, 0); RDB(bvA, 1, 0); RDA(avB, 1, 1, 0);
        stageA(0, 0, t1 + 1);
        PGO; MFMA16R(0, avA, bvA); PSO;
        RDA(avA, 1, 0, 1); RDB(bvB, 1, 1);
        stageA(0, 1, t1 + 1);
        PGO; MFMA16R(4, avB, bvA); PSO;
        RDA(avB, 1, 1, 1);
        PGO; MFMA16R(0, avA, bvB); PSO;
        BARR;                                 // all buf1-B reads drained
        // P8: stage B1 <- t1+2; vmcnt(4) drains B0 + A0
        stageB(1, 0, t1 + 2); stageB(1, 1, t1 + 2);
        PGO; MFMA16R(4, avB, bvB); PSO;
        BARRV(4);
    }

    // final iteration (t0=190 in buf0, t1=191 in buf1); A1<-191 staged here
    {
        RDA(avA, 0, 0, 0); RDB(bvA, 0, 0); RDA(avB, 0, 1, 0);
        stageA(1, 0, 191);
        PGO; MFMA16R(0, avA, bvA); PSO;
        RDA(avA, 0, 0, 1); RDB(bvB, 0, 1);
        stageA(1, 1, 191);
        PGO; MFMA16R(4, avB, bvA); PSO;
        RDA(avB, 0, 1, 1);
        PGO; MFMA16R(0, avA, bvB); PSO;
        PGO; MFMA16R(4, avB, bvB); PSO;
        BARRV(0);
        RDA(avA, 1, 0, 0); RDB(bvA, 1, 0); RDA(avB, 1, 1, 0);
        PGO; MFMA16R(0, avA, bvA); PSO;
        RDA(avA, 1, 0, 1); RDB(bvB, 1, 1);
        PGO; MFMA16R(4, avB, bvA); PSO;
        RDA(avB, 1, 1, 1);
        PGO; MFMA16R(0, avA, bvB); PSO;
        PGO; MFMA16R(4, avB, bvB); PSO;
    }
    __syncthreads();

    // ---------- LDS-staged vectorized epilogue ----------
    // C/D 16x16 layout: col = lane&15, row = (lane>>4)*4 + r.
    int ci = cip[0];
    float wf = wfinP[b];
    const float* resid = lo + (((size_t)ci * BATCH + b) * SEQ + s0) * HID;
    float* op = out + ((size_t)b * SEQ + s0) * HID;
    float* ldsf = reinterpret_cast<float*>(ldsu);

    int rl16 = tid >> 4;          // 0..31
    int c16 = tid & 15;

    #pragma unroll 1
    for (int chunk = 0; chunk < 2; ++chunk) {
        if (wm == chunk) {
            #pragma unroll
            for (int m = 0; m < 8; ++m) {
                int rbase = m * 16 + (lane >> 4) * 4;
                #pragma unroll
                for (int n = 0; n < 4; ++n) {
                    int col64 = n * 16 + (lane & 15);
                    #pragma unroll
                    for (int r = 0; r < 4; ++r) {
                        int rl = rbase + r;
                        int colw = wn * 64 + (col64 ^ (((rl >> 2) & 1) << 4));
                        ldsf[rl * 256 + colw] = acc[m][n][r];
                    }
                }
            }
        }
        __syncthreads();
        #pragma unroll
        for (int p = 0; p < 4; ++p) {
            int rloc = p * 32 + rl16;
            int stag = ((rloc >> 2) & 1) << 4;
            int grow = chunk * 128 + rloc;
            const float* rrow = resid + (size_t)grow * HID + n0;
            float* orow = op + (size_t)grow * HID + n0;
            const float* brow = biasb + b * HID + n0;
            const float* lrow = ldsf + rloc * 256;
            #pragma unroll
            for (int seg = 0; seg < 4; ++seg) {
                int cl = seg * 64 + c16 * 4;
                float4 v = *reinterpret_cast<const float4*>(lrow + (cl ^ stag));
                float4 bs = *reinterpret_cast<const float4*>(brow + cl);
                float4 rs = *reinterpret_cast<const float4*>(rrow + cl);
                float4 o;
                o.x = v.x * wf + bs.x + rs.x;
                o.y = v.y * wf + bs.y + rs.y;
                o.z = v.z * wf + bs.z + rs.z;
                o.w = v.w * wf + bs.w + rs.w;
                *reinterpret_cast<float4*>(orow + cl) = o;
            }
        }
        __syncthreads();
    }
}

// ---------------- fallback: round-2 128^2 gload_lds GEMM (proven) ----------------
#define BM 128
#define BN 128
#define BK 64
#define NT (KTOT / BK)    // 192

__global__ __launch_bounds__(256, 2) void gemm128_kernel(
    const float* __restrict__ lo, const ushortT* __restrict__ Abf,
    const ushortT* __restrict__ Btp, const float* __restrict__ ratioP,
    const float* __restrict__ wfinP, const float* __restrict__ biasb,
    const int* __restrict__ cip, float* __restrict__ out)
{
    __shared__ ushortT lA[2][BM * BK];
    __shared__ ushortT lB[2][BN * BK];
    int t = threadIdx.x;
    int bid = blockIdx.x;
    int xcd = bid & 7, local = bid >> 3;
    int by = xcd * 16 + (local >> 3);
    int bx = local & 7;
    int b = by >> 4;
    int s0 = (by & 15) << 7;
    int n0 = bx << 7;
    int wid = t >> 6, lane = t & 63;
    int wr = wid >> 1, wc = wid & 1;
    int m16 = lane & 15, kb = lane >> 4;
    int aBase[4], bBase[4], ldsBase[4];
    #pragma unroll
    for (int i = 0; i < 4; ++i) {
        int ci2 = i * 256 + t;
        int row = ci2 >> 3, c = ci2 & 7;
        int sw = c ^ (row & 7);
        aBase[i] = (s0 + row) * HID + sw * 8;
        bBase[i] = (n0 + row) * KTOT + sw * 8;
        ldsBase[i] = i * 2048 + wid * 512;
    }
    int aoff[4][2], boff[4][2];
    #pragma unroll
    for (int i = 0; i < 4; ++i) {
        int ra = wr * 64 + i * 16 + m16;
        int rb = wc * 64 + i * 16 + m16;
        #pragma unroll
        for (int kk = 0; kk < 2; ++kk) {
            aoff[i][kk] = ra * 64 + (((kb + 4 * kk) ^ (ra & 7)) * 8);
            boff[i][kk] = rb * 64 + (((kb + 4 * kk) ^ (rb & 7)) * 8);
        }
    }
    f32x4 acc[4][4];
    #pragma unroll
    for (int i = 0; i < 4; ++i)
        #pragma unroll
        for (int j = 0; j < 4; ++j)
            acc[i][j] = (f32x4){0.f, 0.f, 0.f, 0.f};
    auto stage = [&](int buf, int tk2) {
        int l = tk2 >> 4;
        const ushortT* aT = Abf + (size_t)(l * BATCH + b) * (SEQ * HID) + ((tk2 & 15) << 6);
        const ushortT* bT = Btp + ((size_t)tk2 << 6);
        ushortT* la = &lA[buf][0];
        ushortT* lb = &lB[buf][0];
        #pragma unroll
        for (int i = 0; i < 4; ++i)
            __builtin_amdgcn_global_load_lds(
                (const __attribute__((address_space(1))) void*)(aT + aBase[i]),
                (__attribute__((address_space(3))) void*)(la + ldsBase[i]), 16, 0, 0);
        #pragma unroll
        for (int i = 0; i < 4; ++i)
            __builtin_amdgcn_global_load_lds(
                (const __attribute__((address_space(1))) void*)(bT + bBase[i]),
                (__attribute__((address_space(3))) void*)(lb + ldsBase[i]), 16, 0, 0);
    };
    stage(0, 0);
    __syncthreads();
    for (int tk = 0; tk < NT; ++tk) {
        int cur = tk & 1;
        if (tk + 1 < NT) stage(cur ^ 1, tk + 1);
        bf16x8 av[4][2], bv[4][2];
        #pragma unroll
        for (int i = 0; i < 4; ++i) {
            av[i][0] = *reinterpret_cast<const bf16x8*>(&lA[cur][aoff[i][0]]);
            av[i][1] = *reinterpret_cast<const bf16x8*>(&lA[cur][aoff[i][1]]);
            bv[i][0] = *reinterpret_cast<const bf16x8*>(&lB[cur][boff[i][0]]);
            bv[i][1] = *reinterpret_cast<const bf16x8*>(&lB[cur][boff[i][1]]);
        }
        if ((tk & 15) == 0 && tk) {
            float rr = ratioP[b * 16 + (tk >> 4)];
            #pragma unroll
            for (int i = 0; i < 4; ++i)
                #pragma unroll
                for (int j = 0; j < 4; ++j)
                    acc[i][j] = acc[i][j] * rr;
        }
        #pragma unroll
        for (int kk = 0; kk < 2; ++kk)
            #pragma unroll
            for (int fm = 0; fm < 4; ++fm)
                #pragma unroll
                for (int fn = 0; fn < 4; ++fn)
                    acc[fm][fn] = MM(av[fm][kk], bv[fn][kk], acc[fm][fn]);
        __syncthreads();
    }
    int ci = cip[0];
    float wf = wfinP[b];
    const float* resid = lo + (((size_t)ci * BATCH + b) * SEQ + s0) * HID;
    float* op = out + ((size_t)b * SEQ + s0) * HID;
    #pragma unroll
    for (int fn = 0; fn < 4; ++fn) {
        int col = n0 + wc * 64 + fn * 16 + m16;
        float bs = biasb[b * HID + col];
        #pragma unroll
        for (int fm = 0; fm < 4; ++fm) {
            int rbase = wr * 64 + fm * 16 + kb * 4;
            #pragma unroll
            for (int r = 0; r < 4; ++r) {
                float v = acc[fm][fn][r] * wf + bs + resid[(size_t)(rbase + r) * HID + col];
                op[(size_t)(rbase + r) * HID + col] = v;
            }
        }
    }
}

extern "C" void kernel_launch(void* const* d_in, const int* in_sizes, int n_in,
                              void* d_out, int out_size, void* d_ws, size_t ws_size,
                              hipStream_t stream) {
    const float* lo  = (const float*)d_in[0];
    const float* cw  = (const float*)d_in[1];
    const float* mU  = (const float*)d_in[2];
    const float* mV  = (const float*)d_in[3];
    const float* W1  = (const float*)d_in[4];
    const float* b1  = (const float*)d_in[5];
    const float* lnw = (const float*)d_in[6];
    const float* lnb = (const float*)d_in[7];
    const float* W2  = (const float*)d_in[8];
    const float* b2  = (const float*)d_in[9];
    const float* pW  = (const float*)d_in[10];
    const float* pb  = (const float*)d_in[11];
    const int*   ci  = (const int*)d_in[12];
    float* out = (float*)d_out;

    float* pooled = (float*)d_ws;                          // 98304 f
    float* gateb  = pooled + 98304;
    float* wsc    = gateb + 96;
    float* ratio  = wsc + 96;
    float* wfin   = ratio + 128;
    float* biasb  = wfin + 8;
    ushortT* Btp  = (ushortT*)((char*)d_ws + 458752);      // 25165824 B
    ushortT* Abf  = (ushortT*)((char*)d_ws + 25624576);    // 402653184 B
    const size_t need = 25624576ULL + 402653184ULL;

    int fast = (ws_size >= need) ? 1 : 0;

    hipMemsetAsync(pooled, 0, 98304 * sizeof(float), stream);
    streams_kernel<<<dim3(1536 + 3072), 256, 0, stream>>>(lo, pooled, Abf, fast, pW, Btp);
    gate_kernel<<<96, 256, 0, stream>>>(pooled, W1, b1, lnw, lnb, W2, b2, gateb);
    prep_kernel<<<1, 256, 0, stream>>>(cw, mU, mV, gateb, pb, ci, wsc, ratio, wfin, biasb);
    if (fast) {
        gemm8_kernel<<<dim3(256), 512, 0, stream>>>(lo, Abf, Btp, ratio, wfin, biasb, ci, out);
    } else {
        gemm128_kernel<<<dim3(1024), 256, 0, stream>>>(lo, Abf, Btp, ratio, wfin, biasb, ci, out);
    }
}

// Round 12
// 647.510 us; speedup vs baseline: 1.0368x; 1.0087x over previous
//
#include <hip/hip_runtime.h>
#include <hip/hip_bf16.h>
#include <math.h>

#define L_LAYERS 12
#define BATCH 8
#define SEQ 2048
#define HID 1024
#define DGATE 256
#define KTOT (L_LAYERS * HID)   // 12288
#define MTOT (BATCH * SEQ)      // 16384

typedef __attribute__((ext_vector_type(4))) float f32x4;
typedef __attribute__((ext_vector_type(8))) short bf16x8;
typedef unsigned short ushortT;

static __device__ __forceinline__ unsigned short f2bf(float x) {
    __hip_bfloat16 h = __float2bfloat16(x);
    return *reinterpret_cast<unsigned short*>(&h);
}

// ---------------- merged: pool(+bf16 convert of A) and transB ----------------
__global__ void streams_kernel(const float* __restrict__ lo, float* __restrict__ pooled,
                               ushortT* __restrict__ Abf, int doConv,
                               const float* __restrict__ W, ushortT* __restrict__ Bt) {
    __shared__ ushortT tile[64][72];
    int bid = blockIdx.x;
    int t = threadIdx.x;
    if (bid < 1536) {
        int lb = bid % 96;
        int sc = bid / 96;
        const float4* src = reinterpret_cast<const float4*>(lo + (size_t)lb * SEQ * HID);
        ushortT* dstb = Abf + (size_t)lb * SEQ * HID;
        float4 acc = {0.f, 0.f, 0.f, 0.f};
        int s0 = sc * 128;
        if (doConv) {
            #pragma unroll 4
            for (int s = s0; s < s0 + 128; ++s) {
                float4 v = src[(size_t)s * 256 + t];
                acc.x += v.x; acc.y += v.y; acc.z += v.z; acc.w += v.w;
                unsigned int u0 = (unsigned int)f2bf(v.x) | ((unsigned int)f2bf(v.y) << 16);
                unsigned int u1 = (unsigned int)f2bf(v.z) | ((unsigned int)f2bf(v.w) << 16);
                uint2 uu = {u0, u1};
                *reinterpret_cast<uint2*>(dstb + (size_t)s * HID + t * 4) = uu;
            }
        } else {
            #pragma unroll 4
            for (int s = s0; s < s0 + 128; ++s) {
                float4 v = src[(size_t)s * 256 + t];
                acc.x += v.x; acc.y += v.y; acc.z += v.z; acc.w += v.w;
            }
        }
        float* dst = pooled + (size_t)lb * HID + t * 4;
        atomicAdd(dst + 0, acc.x);
        atomicAdd(dst + 1, acc.y);
        atomicAdd(dst + 2, acc.z);
        atomicAdd(dst + 3, acc.w);
    } else {
        int idx = bid - 1536;
        int k0 = (idx % 192) * 64, n0 = (idx / 192) * 64;
        #pragma unroll
        for (int p = 0; p < 4; ++p) {
            int r = (t >> 4) + p * 16;
            int c = (t & 15) * 4;
            float4 v = *reinterpret_cast<const float4*>(W + (size_t)(k0 + r) * HID + n0 + c);
            tile[c + 0][r] = f2bf(v.x);
            tile[c + 1][r] = f2bf(v.y);
            tile[c + 2][r] = f2bf(v.z);
            tile[c + 3][r] = f2bf(v.w);
        }
        __syncthreads();
        #pragma unroll
        for (int p = 0; p < 2; ++p) {
            int idx2 = t + p * 256;
            int nl = idx2 >> 3;
            int kc = (idx2 & 7) * 8;
            uint4 v = *reinterpret_cast<const uint4*>(&tile[nl][kc]);
            *reinterpret_cast<uint4*>(Bt + (size_t)(n0 + nl) * KTOT + k0 + kc) = v;
        }
    }
}

// ---------------- gate MLP: one block per (l,b) ----------------
__global__ void gate_kernel(const float* __restrict__ pooled, const float* __restrict__ W1,
                            const float* __restrict__ b1, const float* __restrict__ lnw,
                            const float* __restrict__ lnb, const float* __restrict__ W2,
                            const float* __restrict__ b2, float* __restrict__ gate) {
    int lb = blockIdx.x;
    int l = lb >> 3;
    __shared__ float sp[HID];
    __shared__ float red[256];
    __shared__ float stat[2];
    int t = threadIdx.x;
    for (int i = t; i < HID; i += 256) sp[i] = pooled[(size_t)lb * HID + i] * (1.0f / 2048.0f);
    __syncthreads();
    const float* w1 = W1 + (size_t)l * HID * DGATE + t;
    float h = b1[l * DGATE + t];
    #pragma unroll 8
    for (int hh = 0; hh < HID; ++hh) h = fmaf(sp[hh], w1[(size_t)hh * DGATE], h);
    red[t] = h; __syncthreads();
    for (int o = 128; o > 0; o >>= 1) { if (t < o) red[t] += red[t + o]; __syncthreads(); }
    if (t == 0) stat[0] = red[0] * (1.0f / 256.0f);
    __syncthreads();
    float mu = stat[0];
    float c = h - mu;
    red[t] = c * c; __syncthreads();
    for (int o = 128; o > 0; o >>= 1) { if (t < o) red[t] += red[t + o]; __syncthreads(); }
    if (t == 0) stat[1] = red[0] * (1.0f / 256.0f);
    __syncthreads();
    float hn = c * rsqrtf(stat[1] + 1e-5f) * lnw[l * DGATE + t] + lnb[l * DGATE + t];
    float hg = hn * 0.5f * (1.0f + erff(hn * 0.70710678118654752f));
    red[t] = hg * W2[l * DGATE + t]; __syncthreads();
    for (int o = 128; o > 0; o >>= 1) { if (t < o) red[t] += red[t + o]; __syncthreads(); }
    if (t == 0) gate[lb] = 1.0f / (1.0f + expf(-(red[0] + b2[l])));
}

// ---------------- prep: m, w, ratios (Horner), bias ----------------
__global__ void prep_kernel(const float* __restrict__ cw, const float* __restrict__ U,
                            const float* __restrict__ V, const float* __restrict__ gate,
                            const float* __restrict__ projb, const int* __restrict__ cip,
                            float* __restrict__ wscale, float* __restrict__ ratio,
                            float* __restrict__ wfin, float* __restrict__ bias) {
    __shared__ float sm[L_LAYERS];
    __shared__ float sw[L_LAYERS * BATCH];
    int t = threadIdx.x;
    int ci = cip[0];
    if (t == 0) {
        float m[L_LAYERS];
        for (int i = 0; i < L_LAYERS; ++i) {
            float mm = cw[ci * L_LAYERS + i];
            float man = 0.f;
            for (int j = 0; j < 32; ++j) man = fmaf(U[ci * 32 + j], V[j * L_LAYERS + i], man);
            m[i] = 0.5f * mm + 0.5f * man;
        }
        for (int rep = 0; rep < 2; ++rep) {
            float mx = -1e30f;
            for (int i = 0; i < L_LAYERS; ++i) mx = fmaxf(mx, m[i]);
            float s = 0.f;
            for (int i = 0; i < L_LAYERS; ++i) { m[i] = expf(m[i] - mx); s += m[i]; }
            float inv = 1.0f / s;
            for (int i = 0; i < L_LAYERS; ++i) m[i] *= inv;
        }
        for (int i = 0; i < L_LAYERS; ++i) sm[i] = m[i];
    }
    __syncthreads();
    if (t < L_LAYERS * BATCH) {
        int l = t >> 3;
        float w = 0.9f * sm[l] * gate[t];
        sw[t] = w;
        wscale[t] = w;
    }
    __syncthreads();
    if (t < BATCH) {
        for (int l = 0; l < L_LAYERS; ++l) {
            float r = (l == 0) ? 1.0f : (sw[(l - 1) * BATCH + t] / sw[l * BATCH + t]);
            ratio[t * 16 + l] = r;
        }
        wfin[t] = sw[(L_LAYERS - 1) * BATCH + t];
    }
    for (int i = t; i < BATCH * HID; i += 256) {
        int b = i >> 10, k = i & 1023;
        float acc = 0.f;
        for (int l = 0; l < L_LAYERS; ++l) acc = fmaf(sw[l * BATCH + b], projb[l * HID + k], acc);
        bias[i] = acc;
    }
}

// ===== 256x256 GEMM, 16x16x32 MFMA, [256][64]+XOR(row&7), pinned pre-reads + 4 barriers/iter =====

#define MM(a, bb, c) __builtin_amdgcn_mfma_f32_16x16x32_bf16(a, bb, c, 0, 0, 0)

#define LDSA(d, off) (*(const bf16x8*)(ldsu + (d) * 16384 + (off)))
#define LDSB(d, off) (*(const bf16x8*)(ldsu + 32768 + (d) * 16384 + (off)))

// read A group g (rows 4g..4g+3 of wave's 8) k-half kk of buf d into dst[0..3]
#define RDA(dst, d, g, kk) { \
    dst[0] = LDSA(d, aK[kk] + ((g) * 4 + 0) * 1024); \
    dst[1] = LDSA(d, aK[kk] + ((g) * 4 + 1) * 1024); \
    dst[2] = LDSA(d, aK[kk] + ((g) * 4 + 2) * 1024); \
    dst[3] = LDSA(d, aK[kk] + ((g) * 4 + 3) * 1024); }

#define RDB(dst, d, kk) { \
    dst[0] = LDSB(d, bK[kk] + 0 * 1024); \
    dst[1] = LDSB(d, bK[kk] + 1 * 1024); \
    dst[2] = LDSB(d, bK[kk] + 2 * 1024); \
    dst[3] = LDSB(d, bK[kk] + 3 * 1024); }

#define MFMA16R(mb, A, B) { \
    acc[(mb)+0][0] = MM(A[0], B[0], acc[(mb)+0][0]); acc[(mb)+0][1] = MM(A[0], B[1], acc[(mb)+0][1]); \
    acc[(mb)+0][2] = MM(A[0], B[2], acc[(mb)+0][2]); acc[(mb)+0][3] = MM(A[0], B[3], acc[(mb)+0][3]); \
    acc[(mb)+1][0] = MM(A[1], B[0], acc[(mb)+1][0]); acc[(mb)+1][1] = MM(A[1], B[1], acc[(mb)+1][1]); \
    acc[(mb)+1][2] = MM(A[1], B[2], acc[(mb)+1][2]); acc[(mb)+1][3] = MM(A[1], B[3], acc[(mb)+1][3]); \
    acc[(mb)+2][0] = MM(A[2], B[0], acc[(mb)+2][0]); acc[(mb)+2][1] = MM(A[2], B[1], acc[(mb)+2][1]); \
    acc[(mb)+2][2] = MM(A[2], B[2], acc[(mb)+2][2]); acc[(mb)+2][3] = MM(A[2], B[3], acc[(mb)+2][3]); \
    acc[(mb)+3][0] = MM(A[3], B[0], acc[(mb)+3][0]); acc[(mb)+3][1] = MM(A[3], B[1], acc[(mb)+3][1]); \
    acc[(mb)+3][2] = MM(A[3], B[2], acc[(mb)+3][2]); acc[(mb)+3][3] = MM(A[3], B[3], acc[(mb)+3][3]); }

#define PGO   __builtin_amdgcn_s_setprio(1);
#define PSO   __builtin_amdgcn_s_setprio(0);
#define SB0   __builtin_amdgcn_sched_barrier(0);
#define BARR  __builtin_amdgcn_s_barrier(); __builtin_amdgcn_sched_barrier(0);
#define BARRV(n) asm volatile("s_waitcnt vmcnt(" #n ")" ::: "memory"); \
    __builtin_amdgcn_s_barrier(); __builtin_amdgcn_sched_barrier(0);

__global__ __launch_bounds__(512, 2) void gemm8_kernel(
    const float* __restrict__ lo,
    const ushortT* __restrict__ Abf,          // bf16 A (L,B,S,H)
    const ushortT* __restrict__ Btp,          // bf16 Bt[n][k]
    const float* __restrict__ ratioP,         // [8][16]
    const float* __restrict__ wfinP,          // [8]
    const float* __restrict__ biasb,          // [8][1024]
    const int* __restrict__ cip,
    float* __restrict__ out)
{
    __shared__ ushortT ldsu[65536];           // 128 KiB

    const int tid = threadIdx.x;
    const int wid = tid >> 6, lane = tid & 63;
    const int wm = wid >> 2, wn = wid & 3;

    int bid = blockIdx.x;
    int xcd = bid & 7, local = bid >> 3;
    int mt = xcd * 8 + (local >> 2);          // 0..63
    int nt = local & 3;                       // 0..3
    int b = mt >> 3;
    int s0 = (mt & 7) << 8;
    int n0 = nt << 8;

    // staging: thread covers physical chunk (row=tid>>3, c=tid&7) of a 64-row block;
    // global source chunk = c ^ (row&7).
    const int csrc = (tid & 7) ^ ((tid >> 3) & 7);
    const size_t aRow = (size_t)(tid >> 3) * HID + csrc * 8;
    const size_t bRow = (size_t)(n0 + (tid >> 3)) * KTOT + csrc * 8;
    const int ldst = tid * 8;
    const ushortT* aPlane0 = Abf + (size_t)b * (SEQ * HID) + (size_t)s0 * HID;

    auto stageA = [&](int d, int h, int kt) {
        int l = kt >> 4;
        const ushortT* plane = aPlane0 + (size_t)l * (BATCH * SEQ * HID) + ((kt & 15) << 6);
        #pragma unroll
        for (int j = 0; j < 2; ++j) {
            const ushortT* src = plane + (size_t)(h * 128 + j * 64) * HID + aRow;
            ushortT* dst = ldsu + d * 16384 + (h * 128 + j * 64) * 64 + ldst;
            __builtin_amdgcn_global_load_lds(
                (const __attribute__((address_space(1))) void*)src,
                (__attribute__((address_space(3))) void*)dst, 16, 0, 0);
        }
    };
    auto stageB = [&](int d, int h, int kt) {
        const ushortT* baseB = Btp + ((size_t)kt << 6);
        #pragma unroll
        for (int j = 0; j < 2; ++j) {
            const ushortT* src = baseB + (size_t)(h * 128 + j * 64) * KTOT + bRow;
            ushortT* dst = ldsu + 32768 + d * 16384 + (h * 128 + j * 64) * 64 + ldst;
            __builtin_amdgcn_global_load_lds(
                (const __attribute__((address_space(1))) void*)src,
                (__attribute__((address_space(3))) void*)dst, 16, 0, 0);
        }
    };

    // fragment base offsets (ushorts). row = base + frag*16 + (lane&15); frag spacing = 1024.
    // logical chunk = kk*4 + (lane>>4); physical = logical ^ (row&7); row&7 == lane&7.
    int aK[2], bK[2];
    {
        int kb = lane >> 4;
        int c0 = ((kb + 0) ^ (lane & 7)) * 8;
        int c1 = ((kb + 4) ^ (lane & 7)) * 8;
        int ar = (wm * 128 + (lane & 15)) * 64;
        int br = (wn * 64 + (lane & 15)) * 64;
        aK[0] = ar + c0; aK[1] = ar + c1;
        bK[0] = br + c0; bK[1] = br + c1;
    }

    f32x4 acc[8][4];
    #pragma unroll
    for (int m = 0; m < 8; ++m)
        #pragma unroll
        for (int n = 0; n < 4; ++n)
            acc[m][n] = (f32x4){0.f, 0.f, 0.f, 0.f};

    // prologue: A0<-t0 (4), B0<-t0 (4), B1<-t1 (4); first 8 must land.
    stageA(0, 0, 0); stageA(0, 1, 0);
    stageB(0, 0, 0); stageB(0, 1, 0);
    stageB(1, 0, 1); stageB(1, 1, 1);
    asm volatile("s_waitcnt vmcnt(4)" ::: "memory");
    __builtin_amdgcn_s_barrier();
    __builtin_amdgcn_sched_barrier(0);

    bf16x8 avA[4], avB[4], bvA[4], bvB[4];

    #pragma unroll 1
    for (int i = 0; i < 95; ++i) {
        int t1 = 2 * i + 1;
        if (i && !(i & 7)) {                  // entering a new layer: Horner rescale
            float rr = ratioP[b * 16 + (i >> 3)];
            #pragma unroll
            for (int m = 0; m < 8; ++m)
                #pragma unroll
                for (int n = 0; n < 4; ++n)
                    acc[m][n] *= rr;
        }
        // ---- region 1: P1-P3; reads pinned EARLY via sched_barrier(0) after each cluster ----
        // P1: own frags + next phase's A
        RDA(avA, 0, 0, 0); RDB(bvA, 0, 0); RDA(avB, 0, 1, 0);
        SB0;
        stageA(1, 0, t1);
        PGO; MFMA16R(0, avA, bvA); PSO;
        // P2: pre-read P3's frags (A kk1 g0 + B kk1)
        RDA(avA, 0, 0, 1); RDB(bvB, 0, 1);
        SB0;
        stageA(1, 1, t1);
        PGO; MFMA16R(4, avB, bvA); PSO;
        // P3: pre-read P4's frags (A kk1 g1)
        RDA(avB, 0, 1, 1);
        SB0;
        PGO; MFMA16R(0, avA, bvB); PSO;
        BARR;                                 // all buf0-B reads drained by P3's MFMA
        // P4: stage B0 <- t0+2; MFMA from regs only; vmcnt(4) drains prev-B1 + A1
        stageB(0, 0, t1 + 1); stageB(0, 1, t1 + 1);
        PGO; MFMA16R(4, avB, bvB); PSO;
        BARRV(4);
        // ---- region 2: P5-P7 (buf1) ----
        RDA(avA, 1, 0, 0); RDB(bvA, 1, 0); RDA(avB, 1, 1, 0);
        SB0;
        stageA(0, 0, t1 + 1);
        PGO; MFMA16R(0, avA, bvA); PSO;
        RDA(avA, 1, 0, 1); RDB(bvB, 1, 1);
        SB0;
        stageA(0, 1, t1 + 1);
        PGO; MFMA16R(4, avB, bvA); PSO;
        RDA(avB, 1, 1, 1);
        SB0;
        PGO; MFMA16R(0, avA, bvB); PSO;
        BARR;                                 // all buf1-B reads drained
        // P8: stage B1 <- t1+2; vmcnt(4) drains B0 + A0
        stageB(1, 0, t1 + 2); stageB(1, 1, t1 + 2);
        PGO; MFMA16R(4, avB, bvB); PSO;
        BARRV(4);
    }

    // final iteration (t0=190 in buf0, t1=191 in buf1); A1<-191 staged here
    {
        RDA(avA, 0, 0, 0); RDB(bvA, 0, 0); RDA(avB, 0, 1, 0);
        SB0;
        stageA(1, 0, 191);
        PGO; MFMA16R(0, avA, bvA); PSO;
        RDA(avA, 0, 0, 1); RDB(bvB, 0, 1);
        SB0;
        stageA(1, 1, 191);
        PGO; MFMA16R(4, avB, bvA); PSO;
        RDA(avB, 0, 1, 1);
        SB0;
        PGO; MFMA16R(0, avA, bvB); PSO;
        PGO; MFMA16R(4, avB, bvB); PSO;
        BARRV(0);
        RDA(avA, 1, 0, 0); RDB(bvA, 1, 0); RDA(avB, 1, 1, 0);
        SB0;
        PGO; MFMA16R(0, avA, bvA); PSO;
        RDA(avA, 1, 0, 1); RDB(bvB, 1, 1);
        SB0;
        PGO; MFMA16R(4, avB, bvA); PSO;
        RDA(avB, 1, 1, 1);
        SB0;
        PGO; MFMA16R(0, avA, bvB); PSO;
        PGO; MFMA16R(4, avB, bvB); PSO;
    }
    __syncthreads();

    // ---------- LDS-staged vectorized epilogue ----------
    // C/D 16x16 layout: col = lane&15, row = (lane>>4)*4 + r.
    int ci = cip[0];
    float wf = wfinP[b];
    const float* resid = lo + (((size_t)ci * BATCH + b) * SEQ + s0) * HID;
    float* op = out + ((size_t)b * SEQ + s0) * HID;
    float* ldsf = reinterpret_cast<float*>(ldsu);

    int rl16 = tid >> 4;          // 0..31
    int c16 = tid & 15;

    #pragma unroll 1
    for (int chunk = 0; chunk < 2; ++chunk) {
        if (wm == chunk) {
            #pragma unroll
            for (int m = 0; m < 8; ++m) {
                int rbase = m * 16 + (lane >> 4) * 4;
                #pragma unroll
                for (int n = 0; n < 4; ++n) {
                    int col64 = n * 16 + (lane & 15);
                    #pragma unroll
                    for (int r = 0; r < 4; ++r) {
                        int rl = rbase + r;
                        int colw = wn * 64 + (col64 ^ (((rl >> 2) & 1) << 4));
                        ldsf[rl * 256 + colw] = acc[m][n][r];
                    }
                }
            }
        }
        __syncthreads();
        #pragma unroll
        for (int p = 0; p < 4; ++p) {
            int rloc = p * 32 + rl16;
            int stag = ((rloc >> 2) & 1) << 4;
            int grow = chunk * 128 + rloc;
            const float* rrow = resid + (size_t)grow * HID + n0;
            float* orow = op + (size_t)grow * HID + n0;
            const float* brow = biasb + b * HID + n0;
            const float* lrow = ldsf + rloc * 256;
            #pragma unroll
            for (int seg = 0; seg < 4; ++seg) {
                int cl = seg * 64 + c16 * 4;
                float4 v = *reinterpret_cast<const float4*>(lrow + (cl ^ stag));
                float4 bs = *reinterpret_cast<const float4*>(brow + cl);
                float4 rs = *reinterpret_cast<const float4*>(rrow + cl);
                float4 o;
                o.x = v.x * wf + bs.x + rs.x;
                o.y = v.y * wf + bs.y + rs.y;
                o.z = v.z * wf + bs.z + rs.z;
                o.w = v.w * wf + bs.w + rs.w;
                *reinterpret_cast<float4*>(orow + cl) = o;
            }
        }
        __syncthreads();
    }
}

// ---------------- fallback: round-2 128^2 gload_lds GEMM (proven) ----------------
#define BM 128
#define BN 128
#define BK 64
#define NT (KTOT / BK)    // 192

__global__ __launch_bounds__(256, 2) void gemm128_kernel(
    const float* __restrict__ lo, const ushortT* __restrict__ Abf,
    const ushortT* __restrict__ Btp, const float* __restrict__ ratioP,
    const float* __restrict__ wfinP, const float* __restrict__ biasb,
    const int* __restrict__ cip, float* __restrict__ out)
{
    __shared__ ushortT lA[2][BM * BK];
    __shared__ ushortT lB[2][BN * BK];
    int t = threadIdx.x;
    int bid = blockIdx.x;
    int xcd = bid & 7, local = bid >> 3;
    int by = xcd * 16 + (local >> 3);
    int bx = local & 7;
    int b = by >> 4;
    int s0 = (by & 15) << 7;
    int n0 = bx << 7;
    int wid = t >> 6, lane = t & 63;
    int wr = wid >> 1, wc = wid & 1;
    int m16 = lane & 15, kb = lane >> 4;
    int aBase[4], bBase[4], ldsBase[4];
    #pragma unroll
    for (int i = 0; i < 4; ++i) {
        int ci2 = i * 256 + t;
        int row = ci2 >> 3, c = ci2 & 7;
        int sw = c ^ (row & 7);
        aBase[i] = (s0 + row) * HID + sw * 8;
        bBase[i] = (n0 + row) * KTOT + sw * 8;
        ldsBase[i] = i * 2048 + wid * 512;
    }
    int aoff[4][2], boff[4][2];
    #pragma unroll
    for (int i = 0; i < 4; ++i) {
        int ra = wr * 64 + i * 16 + m16;
        int rb = wc * 64 + i * 16 + m16;
        #pragma unroll
        for (int kk = 0; kk < 2; ++kk) {
            aoff[i][kk] = ra * 64 + (((kb + 4 * kk) ^ (ra & 7)) * 8);
            boff[i][kk] = rb * 64 + (((kb + 4 * kk) ^ (rb & 7)) * 8);
        }
    }
    f32x4 acc[4][4];
    #pragma unroll
    for (int i = 0; i < 4; ++i)
        #pragma unroll
        for (int j = 0; j < 4; ++j)
            acc[i][j] = (f32x4){0.f, 0.f, 0.f, 0.f};
    auto stage = [&](int buf, int tk2) {
        int l = tk2 >> 4;
        const ushortT* aT = Abf + (size_t)(l * BATCH + b) * (SEQ * HID) + ((tk2 & 15) << 6);
        const ushortT* bT = Btp + ((size_t)tk2 << 6);
        ushortT* la = &lA[buf][0];
        ushortT* lb = &lB[buf][0];
        #pragma unroll
        for (int i = 0; i < 4; ++i)
            __builtin_amdgcn_global_load_lds(
                (const __attribute__((address_space(1))) void*)(aT + aBase[i]),
                (__attribute__((address_space(3))) void*)(la + ldsBase[i]), 16, 0, 0);
        #pragma unroll
        for (int i = 0; i < 4; ++i)
            __builtin_amdgcn_global_load_lds(
                (const __attribute__((address_space(1))) void*)(bT + bBase[i]),
                (__attribute__((address_space(3))) void*)(lb + ldsBase[i]), 16, 0, 0);
    };
    stage(0, 0);
    __syncthreads();
    for (int tk = 0; tk < NT; ++tk) {
        int cur = tk & 1;
        if (tk + 1 < NT) stage(cur ^ 1, tk + 1);
        bf16x8 av[4][2], bv[4][2];
        #pragma unroll
        for (int i = 0; i < 4; ++i) {
            av[i][0] = *reinterpret_cast<const bf16x8*>(&lA[cur][aoff[i][0]]);
            av[i][1] = *reinterpret_cast<const bf16x8*>(&lA[cur][aoff[i][1]]);
            bv[i][0] = *reinterpret_cast<const bf16x8*>(&lB[cur][boff[i][0]]);
            bv[i][1] = *reinterpret_cast<const bf16x8*>(&lB[cur][boff[i][1]]);
        }
        if ((tk & 15) == 0 && tk) {
            float rr = ratioP[b * 16 + (tk >> 4)];
            #pragma unroll
            for (int i = 0; i < 4; ++i)
                #pragma unroll
                for (int j = 0; j < 4; ++j)
                    acc[i][j] = acc[i][j] * rr;
        }
        #pragma unroll
        for (int kk = 0; kk < 2; ++kk)
            #pragma unroll
            for (int fm = 0; fm < 4; ++fm)
                #pragma unroll
                for (int fn = 0; fn < 4; ++fn)
                    acc[fm][fn] = MM(av[fm][kk], bv[fn][kk], acc[fm][fn]);
        __syncthreads();
    }
    int ci = cip[0];
    float wf = wfinP[b];
    const float* resid = lo + (((size_t)ci * BATCH + b) * SEQ + s0) * HID;
    float* op = out + ((size_t)b * SEQ + s0) * HID;
    #pragma unroll
    for (int fn = 0; fn < 4; ++fn) {
        int col = n0 + wc * 64 + fn * 16 + m16;
        float bs = biasb[b * HID + col];
        #pragma unroll
        for (int fm = 0; fm < 4; ++fm) {
            int rbase = wr * 64 + fm * 16 + kb * 4;
            #pragma unroll
            for (int r = 0; r < 4; ++r) {
                float v = acc[fm][fn][r] * wf + bs + resid[(size_t)(rbase + r) * HID + col];
                op[(size_t)(rbase + r) * HID + col] = v;
            }
        }
    }
}

extern "C" void kernel_launch(void* const* d_in, const int* in_sizes, int n_in,
                              void* d_out, int out_size, void* d_ws, size_t ws_size,
                              hipStream_t stream) {
    const float* lo  = (const float*)d_in[0];
    const float* cw  = (const float*)d_in[1];
    const float* mU  = (const float*)d_in[2];
    const float* mV  = (const float*)d_in[3];
    const float* W1  = (const float*)d_in[4];
    const float* b1  = (const float*)d_in[5];
    const float* lnw = (const float*)d_in[6];
    const float* lnb = (const float*)d_in[7];
    const float* W2  = (const float*)d_in[8];
    const float* b2  = (const float*)d_in[9];
    const float* pW  = (const float*)d_in[10];
    const float* pb  = (const float*)d_in[11];
    const int*   ci  = (const int*)d_in[12];
    float* out = (float*)d_out;

    float* pooled = (float*)d_ws;                          // 98304 f
    float* gateb  = pooled + 98304;
    float* wsc    = gateb + 96;
    float* ratio  = wsc + 96;
    float* wfin   = ratio + 128;
    float* biasb  = wfin + 8;
    ushortT* Btp  = (ushortT*)((char*)d_ws + 458752);      // 25165824 B
    ushortT* Abf  = (ushortT*)((char*)d_ws + 25624576);    // 402653184 B
    const size_t need = 25624576ULL + 402653184ULL;

    int fast = (ws_size >= need) ? 1 : 0;

    hipMemsetAsync(pooled, 0, 98304 * sizeof(float), stream);
    streams_kernel<<<dim3(1536 + 3072), 256, 0, stream>>>(lo, pooled, Abf, fast, pW, Btp);
    gate_kernel<<<96, 256, 0, stream>>>(pooled, W1, b1, lnw, lnb, W2, b2, gateb);
    prep_kernel<<<1, 256, 0, stream>>>(cw, mU, mV, gateb, pb, ci, wsc, ratio, wfin, biasb);
    if (fast) {
        gemm8_kernel<<<dim3(256), 512, 0, stream>>>(lo, Abf, Btp, ratio, wfin, biasb, ci, out);
    } else {
        gemm128_kernel<<<dim3(1024), 256, 0, stream>>>(lo, Abf, Btp, ratio, wfin, biasb, ci, out);
    }
}